// Round 1
// baseline (1602.493 us; speedup 1.0000x reference)
//
#include <hip/hip_runtime.h>
#include <math.h>

#define D_MODEL   512
#define D_INNER   1024
#define NHEADS    16
#define HEADDIM   64
#define D_STATE   64
#define D_CONV    7
#define D_FF      2048
#define CONV_DIM  1152          // D_INNER + 2*D_STATE
#define D_IN_PROJ 2208          // 2*D_INNER + 2*D_STATE + 2*NHEADS
#define BATCH     4
#define SEQLEN    2048
#define NTOK      (BATCH*SEQLEN)   // 8192
#define EPS       1e-5f

// ---------------- helpers ----------------
__device__ __forceinline__ float siluf(float x) { return x / (1.f + expf(-x)); }
__device__ __forceinline__ float geluf(float x) { return 0.5f * x * (1.f + erff(x * 0.70710678118654752f)); }
__device__ __forceinline__ float softplusf(float x) { return fmaxf(x, 0.f) + log1pf(expf(-fabsf(x))); }

// ---------------- LayerNorm: one wave (64 lanes) per 512-float row ----------------
__global__ __launch_bounds__(256) void ln_kernel(const float* __restrict__ x,
                                                 const float* __restrict__ w,
                                                 const float* __restrict__ b,
                                                 float* __restrict__ out, int nrows)
{
    int wid = threadIdx.x >> 6;
    int lane = threadIdx.x & 63;
    int row = blockIdx.x * 4 + wid;
    if (row >= nrows) return;
    const float* xr = x + (size_t)row * D_MODEL;
    float4 v0 = *(const float4*)(xr + lane * 8);
    float4 v1 = *(const float4*)(xr + lane * 8 + 4);
    float v[8] = {v0.x, v0.y, v0.z, v0.w, v1.x, v1.y, v1.z, v1.w};
    float s = 0.f;
#pragma unroll
    for (int i = 0; i < 8; i++) s += v[i];
#pragma unroll
    for (int m = 1; m < 64; m <<= 1) s += __shfl_xor(s, m, 64);
    float mu = s * (1.f / D_MODEL);
    float q = 0.f;
#pragma unroll
    for (int i = 0; i < 8; i++) { float d = v[i] - mu; q += d * d; }
#pragma unroll
    for (int m = 1; m < 64; m <<= 1) q += __shfl_xor(q, m, 64);
    float inv = rsqrtf(q * (1.f / D_MODEL) + EPS);
    float4 w0 = *(const float4*)(w + lane * 8);
    float4 w1 = *(const float4*)(w + lane * 8 + 4);
    float4 b0 = *(const float4*)(b + lane * 8);
    float4 b1 = *(const float4*)(b + lane * 8 + 4);
    float4 o0, o1;
    o0.x = (v[0]-mu)*inv*w0.x + b0.x; o0.y = (v[1]-mu)*inv*w0.y + b0.y;
    o0.z = (v[2]-mu)*inv*w0.z + b0.z; o0.w = (v[3]-mu)*inv*w0.w + b0.w;
    o1.x = (v[4]-mu)*inv*w1.x + b1.x; o1.y = (v[5]-mu)*inv*w1.y + b1.y;
    o1.z = (v[6]-mu)*inv*w1.z + b1.z; o1.w = (v[7]-mu)*inv*w1.w + b1.w;
    float* orow = out + (size_t)row * D_MODEL;
    *(float4*)(orow + lane * 8) = o0;
    *(float4*)(orow + lane * 8 + 4) = o1;
}

// ---------------- fp32 GEMM: C[M,N] = A[M,K] * W[N,K]^T (+bias)(+res)(gelu) ----------------
#define BM 128
#define BN 64
#define BK 16

__global__ __launch_bounds__(256, 2) void gemm_nt(const float* __restrict__ A,
                                                  const float* __restrict__ W,
                                                  float* __restrict__ C,
                                                  int M, int N, int K,
                                                  const float* __restrict__ bias,
                                                  const float* __restrict__ res, int act)
{
    __shared__ float As[BK][BM + 4];
    __shared__ float Ws[BK][BN + 4];
    const int tid = threadIdx.x;
    const int m0 = blockIdx.y * BM;
    const int n0 = blockIdx.x * BN;
    const int ty = tid >> 4;          // 0..15
    const int tx = tid & 15;          // 0..15
    const int lr = tid >> 2;          // 0..63
    const int kq = (tid & 3) * 4;     // 0,4,8,12
    float acc[8][4] = {};

    for (int k0 = 0; k0 < K; k0 += BK) {
#pragma unroll
        for (int i = 0; i < 2; i++) {
            int r = lr + i * 64;
            float4 v = *(const float4*)(A + (size_t)(m0 + r) * K + (k0 + kq));
            As[kq + 0][r] = v.x; As[kq + 1][r] = v.y; As[kq + 2][r] = v.z; As[kq + 3][r] = v.w;
        }
        {
            float4 v = make_float4(0.f, 0.f, 0.f, 0.f);
            if (n0 + lr < N) v = *(const float4*)(W + (size_t)(n0 + lr) * K + (k0 + kq));
            Ws[kq + 0][lr] = v.x; Ws[kq + 1][lr] = v.y; Ws[kq + 2][lr] = v.z; Ws[kq + 3][lr] = v.w;
        }
        __syncthreads();
#pragma unroll
        for (int kk = 0; kk < BK; kk++) {
            float4 a0 = *(const float4*)&As[kk][ty * 8];
            float4 a1 = *(const float4*)&As[kk][ty * 8 + 4];
            float4 bb = *(const float4*)&Ws[kk][tx * 4];
            float am[8] = {a0.x, a0.y, a0.z, a0.w, a1.x, a1.y, a1.z, a1.w};
            float bn[4] = {bb.x, bb.y, bb.z, bb.w};
#pragma unroll
            for (int i = 0; i < 8; i++)
#pragma unroll
                for (int j = 0; j < 4; j++)
                    acc[i][j] = fmaf(am[i], bn[j], acc[i][j]);
        }
        __syncthreads();
    }
    int n = n0 + tx * 4;
    if (n < N) {
#pragma unroll
        for (int i = 0; i < 8; i++) {
            size_t m = (size_t)(m0 + ty * 8 + i);
            float4 v = make_float4(acc[i][0], acc[i][1], acc[i][2], acc[i][3]);
            if (bias) { v.x += bias[n]; v.y += bias[n + 1]; v.z += bias[n + 2]; v.w += bias[n + 3]; }
            if (res) { float4 r = *(const float4*)(res + m * N + n); v.x += r.x; v.y += r.y; v.z += r.z; v.w += r.w; }
            if (act) { v.x = geluf(v.x); v.y = geluf(v.y); v.z = geluf(v.z); v.w = geluf(v.w); }
            *(float4*)(C + m * N + n) = v;
        }
    }
}

// ---------------- depthwise causal conv (k=7) + bias + SiLU ----------------
__global__ __launch_bounds__(256) void conv_kernel(const float* __restrict__ zxbcdt,
                                                   const float* __restrict__ conv_w,
                                                   const float* __restrict__ conv_b,
                                                   float* __restrict__ out)
{
    int gid = blockIdx.x * 256 + threadIdx.x;
    if (gid >= NTOK * CONV_DIM) return;
    int c = gid % CONV_DIM;
    int bt = gid / CONV_DIM;
    int t = bt & (SEQLEN - 1);
    float acc = conv_b[c];
    const float* base = zxbcdt + (size_t)bt * D_IN_PROJ + D_INNER + c;
#pragma unroll
    for (int j = 0; j < D_CONV; j++) {
        int tt = t - 6 + j;
        if (tt >= 0) acc = fmaf(conv_w[c * D_CONV + j], base[(ptrdiff_t)(j - 6) * D_IN_PROJ], acc);
    }
    out[(size_t)bt * CONV_DIM + c] = siluf(acc);
}

// ---------------- bidirectional SSM scan ----------------
// grid = 2(dir) * 4(batch) * 16(head) * 4(p-split) = 512 blocks, 256 threads.
// State slice: 16 p x 64 n per block; thread (p_local=tid>>4, nq=tid&15) owns n = nq*4..nq*4+3.
#define CH 64
#define PSPLIT 4

__global__ __launch_bounds__(256) void scan_kernel(const float* __restrict__ zxbcdt,
                                                   const float* __restrict__ xbc,
                                                   const float* __restrict__ dt_bias,
                                                   const float* __restrict__ A_log,
                                                   float* __restrict__ y_fw,
                                                   float* __restrict__ y_bw)
{
    int blk = blockIdx.x;
    const int ps = blk & (PSPLIT - 1); blk >>= 2;
    const int h  = blk & (NHEADS - 1); blk >>= 4;
    const int b  = blk & 3;            blk >>= 2;
    const int d  = blk;                 // 0=fwd, 1=bwd
    const int tid = threadIdx.x;
    const int p_local = tid >> 4;       // 0..15
    const int nq = tid & 15;            // 0..15

    __shared__ float xs_c[CH][16];
    __shared__ float B_c[CH][64];
    __shared__ float C_c[CH][64];
    __shared__ float dt_c[CH];
    __shared__ float dec_c[CH];
    __shared__ float y_c[CH][16];

    const float A_h = -expf(A_log[h]);
    const float bias = dt_bias[h];
    float hst[4] = {0.f, 0.f, 0.f, 0.f};
    float* yout = d ? y_bw : y_fw;
    const int pchan = h * HEADDIM + ps * 16;

    // boundary position (fwd t=0 / bwd t=L-1) is defined zero
    if (tid < 16) {
        int t0 = d ? (SEQLEN - 1) : 0;
        yout[((size_t)(b * SEQLEN + t0)) * D_INNER + pchan + tid] = 0.f;
    }

    for (int c0 = 0; c0 < SEQLEN; c0 += CH) {
        for (int idx = tid; idx < CH * 64; idx += 256) {
            int tt = idx >> 6, col = idx & 63;
            int s = c0 + tt;
            int tg = d ? (SEQLEN - 1 - s) : s;
            size_t rb = ((size_t)(b * SEQLEN + tg)) * CONV_DIM;
            B_c[tt][col] = xbc[rb + D_INNER + col];
            C_c[tt][col] = xbc[rb + D_INNER + 64 + col];
        }
        for (int idx = tid; idx < CH * 16; idx += 256) {
            int tt = idx >> 4, col = idx & 15;
            int s = c0 + tt;
            int tg = d ? (SEQLEN - 1 - s) : s;
            xs_c[tt][col] = xbc[((size_t)(b * SEQLEN + tg)) * CONV_DIM + pchan + col];
        }
        if (tid < CH) {
            int s = c0 + tid;
            int tg = d ? (SEQLEN - 1 - s) : s;
            float raw = zxbcdt[((size_t)(b * SEQLEN + tg)) * D_IN_PROJ + (2 * D_INNER + 2 * D_STATE) + d * NHEADS + h] + bias;
            float dtv = softplusf(raw);
            dt_c[tid] = dtv;
            dec_c[tid] = expf(A_h * dtv);
        }
        __syncthreads();
#pragma unroll 4
        for (int tt = 0; tt < CH; tt++) {
            float dec = dec_c[tt];
            float dtx = dt_c[tt] * xs_c[tt][p_local];
            float4 bb = *(const float4*)&B_c[tt][nq * 4];
            float4 cc = *(const float4*)&C_c[tt][nq * 4];
            float bv[4] = {bb.x, bb.y, bb.z, bb.w};
            float cv[4] = {cc.x, cc.y, cc.z, cc.w};
            float part = 0.f;
#pragma unroll
            for (int j = 0; j < 4; j++) {
                hst[j] = fmaf(hst[j], dec, dtx * bv[j]);
                part = fmaf(hst[j], cv[j], part);
            }
            part += __shfl_xor(part, 1, 64);
            part += __shfl_xor(part, 2, 64);
            part += __shfl_xor(part, 4, 64);
            part += __shfl_xor(part, 8, 64);
            if (nq == 0) y_c[tt][p_local] = part;
        }
        __syncthreads();
        for (int idx = tid; idx < CH * 16; idx += 256) {
            int tt = idx >> 4, col = idx & 15;
            int s = c0 + tt;
            int tout = d ? (SEQLEN - 2 - s) : (s + 1);   // output shift by one step
            if (tout >= 0 && tout < SEQLEN)
                yout[((size_t)(b * SEQLEN + tout)) * D_INNER + pchan + col] = y_c[tt][col];
        }
        __syncthreads();
    }
}

// ---------------- combine: y_fw+y_bw+xs*Dp, gate silu(z), RMSNorm -> yg (in-place into y_fw) ----------------
__global__ __launch_bounds__(256) void combine_kernel(const float* __restrict__ zxbcdt,
                                                      const float* __restrict__ xbc,
                                                      const float* __restrict__ y_bw,
                                                      const float* __restrict__ Dp,
                                                      const float* __restrict__ rms_w,
                                                      float* __restrict__ yg)
{
    int row = blockIdx.x;
    int i = threadIdx.x * 4;
    float4 yf = *(const float4*)(yg + (size_t)row * D_INNER + i);
    float4 yb = *(const float4*)(y_bw + (size_t)row * D_INNER + i);
    float4 xs = *(const float4*)(xbc + (size_t)row * CONV_DIM + i);
    float4 z  = *(const float4*)(zxbcdt + (size_t)row * D_IN_PROJ + i);
    float dp = Dp[i >> 6];
    float g[4];
    g[0] = (yf.x + yb.x + xs.x * dp) * siluf(z.x);
    g[1] = (yf.y + yb.y + xs.y * dp) * siluf(z.y);
    g[2] = (yf.z + yb.z + xs.z * dp) * siluf(z.z);
    g[3] = (yf.w + yb.w + xs.w * dp) * siluf(z.w);
    float ss = g[0]*g[0] + g[1]*g[1] + g[2]*g[2] + g[3]*g[3];
#pragma unroll
    for (int m = 1; m < 64; m <<= 1) ss += __shfl_xor(ss, m, 64);
    __shared__ float red[4];
    if ((threadIdx.x & 63) == 0) red[threadIdx.x >> 6] = ss;
    __syncthreads();
    ss = red[0] + red[1] + red[2] + red[3];
    float scale = rsqrtf(ss * (1.f / D_INNER) + EPS);
    float4 rw = *(const float4*)(rms_w + i);
    float4 o;
    o.x = g[0] * scale * rw.x; o.y = g[1] * scale * rw.y;
    o.z = g[2] * scale * rw.z; o.w = g[3] * scale * rw.w;
    *(float4*)(yg + (size_t)row * D_INNER + i) = o;
}

// ---------------- launch ----------------
extern "C" void kernel_launch(void* const* d_in, const int* in_sizes, int n_in,
                              void* d_out, int out_size, void* d_ws, size_t ws_size,
                              hipStream_t stream)
{
    const float* x         = (const float*)d_in[0];
    const float* ln1_w     = (const float*)d_in[1];
    const float* ln1_b     = (const float*)d_in[2];
    const float* in_proj_w = (const float*)d_in[3];
    const float* conv_w    = (const float*)d_in[4];
    const float* conv_b    = (const float*)d_in[5];
    const float* dt_bias   = (const float*)d_in[6];
    const float* A_log     = (const float*)d_in[7];
    const float* Dp        = (const float*)d_in[8];
    const float* rms_w     = (const float*)d_in[9];
    const float* out_proj_w= (const float*)d_in[10];
    const float* ln2_w     = (const float*)d_in[11];
    const float* ln2_b     = (const float*)d_in[12];
    const float* fc1_w     = (const float*)d_in[13];
    const float* fc1_b     = (const float*)d_in[14];
    const float* fc2_w     = (const float*)d_in[15];
    const float* fc2_b     = (const float*)d_in[16];
    float* out = (float*)d_out;

    float* buf_h  = (float*)d_ws;                         // 8192*512   (ln1 out; later ln2 out)
    float* zxbcdt = buf_h + (size_t)NTOK * D_MODEL;       // 8192*2208  (later fc1 out reuses)
    float* xbc    = zxbcdt + (size_t)NTOK * D_IN_PROJ;    // 8192*1152
    float* y_fw   = xbc + (size_t)NTOK * CONV_DIM;        // 8192*1024  (becomes yg in-place)
    float* y_bw   = y_fw + (size_t)NTOK * D_INNER;        // 8192*1024
    float* x_res  = y_bw + (size_t)NTOK * D_INNER;        // 8192*512
    float* f1     = zxbcdt;                               // 8192*2048 fits in zxbcdt region
    float* h2     = buf_h;

    // 1. LN1
    ln_kernel<<<dim3(NTOK / 4), dim3(256), 0, stream>>>(x, ln1_w, ln1_b, buf_h, NTOK);
    // 2. in_proj: (8192,512) @ (2208,512)^T
    gemm_nt<<<dim3((D_IN_PROJ + BN - 1) / BN, NTOK / BM), dim3(256), 0, stream>>>(
        buf_h, in_proj_w, zxbcdt, NTOK, D_IN_PROJ, D_MODEL, nullptr, nullptr, 0);
    // 3. depthwise conv + SiLU
    conv_kernel<<<dim3(NTOK * CONV_DIM / 256), dim3(256), 0, stream>>>(zxbcdt, conv_w, conv_b, xbc);
    // 4. bidirectional scan
    scan_kernel<<<dim3(2 * BATCH * NHEADS * PSPLIT), dim3(256), 0, stream>>>(
        zxbcdt, xbc, dt_bias, A_log, y_fw, y_bw);
    // 5. combine + gate + RMSNorm (yg into y_fw)
    combine_kernel<<<dim3(NTOK), dim3(256), 0, stream>>>(zxbcdt, xbc, y_bw, Dp, rms_w, y_fw);
    // 6. out_proj + residual(x) -> x_res
    gemm_nt<<<dim3(D_MODEL / BN, NTOK / BM), dim3(256), 0, stream>>>(
        y_fw, out_proj_w, x_res, NTOK, D_MODEL, D_INNER, nullptr, x, 0);
    // 7. LN2
    ln_kernel<<<dim3(NTOK / 4), dim3(256), 0, stream>>>(x_res, ln2_w, ln2_b, h2, NTOK);
    // 8. fc1 + bias + GELU
    gemm_nt<<<dim3(D_FF / BN, NTOK / BM), dim3(256), 0, stream>>>(
        h2, fc1_w, f1, NTOK, D_FF, D_MODEL, fc1_b, nullptr, 1);
    // 9. fc2 + bias + residual(x_res) -> out
    gemm_nt<<<dim3(D_MODEL / BN, NTOK / BM), dim3(256), 0, stream>>>(
        f1, fc2_w, out, NTOK, D_MODEL, D_FF, fc2_b, x_res, 0);
}

// Round 2
// 1561.348 us; speedup vs baseline: 1.0264x; 1.0264x over previous
//
#include <hip/hip_runtime.h>
#include <math.h>

#define D_MODEL   512
#define D_INNER   1024
#define NHEADS    16
#define HEADDIM   64
#define D_STATE   64
#define D_CONV    7
#define D_FF      2048
#define CONV_DIM  1152
#define D_IN_PROJ 2208
#define BATCH     4
#define SEQLEN    2048
#define NTOK      (BATCH*SEQLEN)
#define EPS       1e-5f

// ws float offsets
#define OFF_ZX    4194304ull            // buf_h = [0, 4.19M)
#define OFF_XBC   22282240ull
#define OFF_YSUM  31719424ull
#define OFF_S1    40108032ull           // tiles 0..2047   (old y_bw)
#define OFF_S2    48496640ull           // tiles 2048..3071 (x_res region)
// tiles 3072..4095 live at ws[0] (buf_h region, dead during scan)

__device__ __forceinline__ float siluf(float x) { return x / (1.f + expf(-x)); }
__device__ __forceinline__ float geluf(float x) { return 0.5f * x * (1.f + erff(x * 0.70710678118654752f)); }
__device__ __forceinline__ float softplusf(float x) { return fmaxf(x, 0.f) + log1pf(expf(-fabsf(x))); }
__device__ __forceinline__ int tglob(int d, int c, int t) { int s = c * 64 + t; return d ? (SEQLEN - 1 - s) : s; }
__device__ __forceinline__ float* s_tile(float* ws0, int idx) {
    if (idx < 2048) return ws0 + OFF_S1 + (size_t)idx * 4096;
    if (idx < 3072) return ws0 + OFF_S2 + (size_t)(idx - 2048) * 4096;
    return ws0 + (size_t)(idx - 3072) * 4096;
}

// ---------------- LayerNorm ----------------
__global__ __launch_bounds__(256) void ln_kernel(const float* __restrict__ x,
                                                 const float* __restrict__ w,
                                                 const float* __restrict__ b,
                                                 float* __restrict__ out, int nrows)
{
    int wid = threadIdx.x >> 6;
    int lane = threadIdx.x & 63;
    int row = blockIdx.x * 4 + wid;
    if (row >= nrows) return;
    const float* xr = x + (size_t)row * D_MODEL;
    float4 v0 = *(const float4*)(xr + lane * 8);
    float4 v1 = *(const float4*)(xr + lane * 8 + 4);
    float v[8] = {v0.x, v0.y, v0.z, v0.w, v1.x, v1.y, v1.z, v1.w};
    float s = 0.f;
#pragma unroll
    for (int i = 0; i < 8; i++) s += v[i];
#pragma unroll
    for (int m = 1; m < 64; m <<= 1) s += __shfl_xor(s, m, 64);
    float mu = s * (1.f / D_MODEL);
    float q = 0.f;
#pragma unroll
    for (int i = 0; i < 8; i++) { float dd = v[i] - mu; q += dd * dd; }
#pragma unroll
    for (int m = 1; m < 64; m <<= 1) q += __shfl_xor(q, m, 64);
    float inv = rsqrtf(q * (1.f / D_MODEL) + EPS);
    float4 w0 = *(const float4*)(w + lane * 8);
    float4 w1 = *(const float4*)(w + lane * 8 + 4);
    float4 b0 = *(const float4*)(b + lane * 8);
    float4 b1 = *(const float4*)(b + lane * 8 + 4);
    float4 o0, o1;
    o0.x = (v[0]-mu)*inv*w0.x + b0.x; o0.y = (v[1]-mu)*inv*w0.y + b0.y;
    o0.z = (v[2]-mu)*inv*w0.z + b0.z; o0.w = (v[3]-mu)*inv*w0.w + b0.w;
    o1.x = (v[4]-mu)*inv*w1.x + b1.x; o1.y = (v[5]-mu)*inv*w1.y + b1.y;
    o1.z = (v[6]-mu)*inv*w1.z + b1.z; o1.w = (v[7]-mu)*inv*w1.w + b1.w;
    float* orow = out + (size_t)row * D_MODEL;
    *(float4*)(orow + lane * 8) = o0;
    *(float4*)(orow + lane * 8 + 4) = o1;
}

// ---------------- fp32 GEMM: C = A * W^T (+bias)(+res)(gelu) ----------------
#define BM 128
#define BN 64
#define BK 16

__global__ __launch_bounds__(256, 2) void gemm_nt(const float* __restrict__ A,
                                                  const float* __restrict__ W,
                                                  float* __restrict__ C,
                                                  int M, int N, int K,
                                                  const float* __restrict__ bias,
                                                  const float* __restrict__ res, int act)
{
    __shared__ float As[BK][BM + 4];
    __shared__ float Ws[BK][BN + 4];
    const int tid = threadIdx.x;
    const int m0 = blockIdx.y * BM;
    const int n0 = blockIdx.x * BN;
    const int ty = tid >> 4;
    const int tx = tid & 15;
    const int lr = tid >> 2;
    const int kq = (tid & 3) * 4;
    float acc[8][4] = {};

    for (int k0 = 0; k0 < K; k0 += BK) {
#pragma unroll
        for (int i = 0; i < 2; i++) {
            int r = lr + i * 64;
            float4 v = *(const float4*)(A + (size_t)(m0 + r) * K + (k0 + kq));
            As[kq + 0][r] = v.x; As[kq + 1][r] = v.y; As[kq + 2][r] = v.z; As[kq + 3][r] = v.w;
        }
        {
            float4 v = make_float4(0.f, 0.f, 0.f, 0.f);
            if (n0 + lr < N) v = *(const float4*)(W + (size_t)(n0 + lr) * K + (k0 + kq));
            Ws[kq + 0][lr] = v.x; Ws[kq + 1][lr] = v.y; Ws[kq + 2][lr] = v.z; Ws[kq + 3][lr] = v.w;
        }
        __syncthreads();
#pragma unroll
        for (int kk = 0; kk < BK; kk++) {
            float4 a0 = *(const float4*)&As[kk][ty * 8];
            float4 a1 = *(const float4*)&As[kk][ty * 8 + 4];
            float4 bb = *(const float4*)&Ws[kk][tx * 4];
            float am[8] = {a0.x, a0.y, a0.z, a0.w, a1.x, a1.y, a1.z, a1.w};
            float bn[4] = {bb.x, bb.y, bb.z, bb.w};
#pragma unroll
            for (int i = 0; i < 8; i++)
#pragma unroll
                for (int j = 0; j < 4; j++)
                    acc[i][j] = fmaf(am[i], bn[j], acc[i][j]);
        }
        __syncthreads();
    }
    int n = n0 + tx * 4;
    if (n < N) {
#pragma unroll
        for (int i = 0; i < 8; i++) {
            size_t m = (size_t)(m0 + ty * 8 + i);
            float4 v = make_float4(acc[i][0], acc[i][1], acc[i][2], acc[i][3]);
            if (bias) { v.x += bias[n]; v.y += bias[n + 1]; v.z += bias[n + 2]; v.w += bias[n + 3]; }
            if (res) { float4 r = *(const float4*)(res + m * N + n); v.x += r.x; v.y += r.y; v.z += r.z; v.w += r.w; }
            if (act) { v.x = geluf(v.x); v.y = geluf(v.y); v.z = geluf(v.z); v.w = geluf(v.w); }
            *(float4*)(C + m * N + n) = v;
        }
    }
}

// ---------------- depthwise causal conv (k=7) + bias + SiLU ----------------
__global__ __launch_bounds__(256) void conv_kernel(const float* __restrict__ zxbcdt,
                                                   const float* __restrict__ conv_w,
                                                   const float* __restrict__ conv_b,
                                                   float* __restrict__ out)
{
    int gid = blockIdx.x * 256 + threadIdx.x;
    if (gid >= NTOK * CONV_DIM) return;
    int c = gid % CONV_DIM;
    int bt = gid / CONV_DIM;
    int t = bt & (SEQLEN - 1);
    float acc = conv_b[c];
    const float* base = zxbcdt + (size_t)bt * D_IN_PROJ + D_INNER + c;
#pragma unroll
    for (int j = 0; j < D_CONV; j++) {
        int tt = t - 6 + j;
        if (tt >= 0) acc = fmaf(conv_w[c * D_CONV + j], base[(ptrdiff_t)(j - 6) * D_IN_PROJ], acc);
    }
    out[(size_t)bt * CONV_DIM + c] = siluf(acc);
}

// ---------------- K0: dt/cum tables (one wave per (d,b,h,chunk)) ----------------
__global__ __launch_bounds__(256) void dt_table_kernel(const float* __restrict__ zxbcdt,
                                                       const float* __restrict__ dt_bias,
                                                       const float* __restrict__ A_log,
                                                       float* __restrict__ cum_tab,
                                                       float* __restrict__ dtv_tab)
{
    int wid = blockIdx.x * 4 + (threadIdx.x >> 6);
    int lane = threadIdx.x & 63;
    int c = wid & 31, h = (wid >> 5) & 15, b = (wid >> 9) & 3, d = wid >> 11;
    int tg = tglob(d, c, lane);
    float raw = zxbcdt[(size_t)(b * SEQLEN + tg) * D_IN_PROJ + 2176 + d * 16 + h] + dt_bias[h];
    float dtv = softplusf(raw);
    float cum = -expf(A_log[h]) * dtv;
#pragma unroll
    for (int off = 1; off < 64; off <<= 1) {
        int src = lane - off;
        float o = __shfl(cum, src < 0 ? 0 : src, 64);
        if (lane >= off) cum += o;
    }
    cum_tab[(size_t)wid * 64 + lane] = cum;
    dtv_tab[(size_t)wid * 64 + lane] = dtv;
}

// ---------------- zero y_sum ----------------
__global__ __launch_bounds__(256) void zero_kernel(float4* __restrict__ p, int n4)
{
    int i = blockIdx.x * 256 + threadIdx.x;
    if (i < n4) p[i] = make_float4(0.f, 0.f, 0.f, 0.f);
}

// ---------------- K1: intra-chunk Y (block = (d,b,chunk), loops 16 heads, G shared) ----------------
__global__ __launch_bounds__(256) void ssd_intra_kernel(const float* __restrict__ xbc,
                                                        const float* __restrict__ cum_tab,
                                                        const float* __restrict__ dtv_tab,
                                                        float* __restrict__ y_sum)
{
    const int bid = blockIdx.x;
    const int c = bid & 31, b = (bid >> 5) & 3, d = bid >> 7;
    const int tid = threadIdx.x;
    const int ty = tid >> 4, tx = tid & 15;

    __shared__ float B_T[64][68];
    __shared__ float C_T[64][68];
    __shared__ float G_T[64][64];
    __shared__ float M_T[64][64];
    __shared__ float Xs[64][64];
    __shared__ float cum_l[64], dtv_l[64];

    for (int idx = tid; idx < 1024; idx += 256) {
        int s = idx >> 4, q = idx & 15;
        int tg = tglob(d, c, s);
        const float* row = xbc + (size_t)(b * SEQLEN + tg) * CONV_DIM;
        float4 vb = *(const float4*)(row + 1024 + q * 4);
        float4 vc = *(const float4*)(row + 1088 + q * 4);
        B_T[q*4+0][s] = vb.x; B_T[q*4+1][s] = vb.y; B_T[q*4+2][s] = vb.z; B_T[q*4+3][s] = vb.w;
        C_T[q*4+0][s] = vc.x; C_T[q*4+1][s] = vc.y; C_T[q*4+2][s] = vc.z; C_T[q*4+3][s] = vc.w;
    }
    __syncthreads();

    // G_T[s][t] = sum_n B_T[n][s] * C_T[n][t]   (shared across heads)
    {
        float acc[4][4] = {};
        for (int n = 0; n < 64; n++) {
            float4 bv = *(const float4*)&B_T[n][ty * 4];
            float4 cv = *(const float4*)&C_T[n][tx * 4];
            float bb[4] = {bv.x, bv.y, bv.z, bv.w};
            float cc[4] = {cv.x, cv.y, cv.z, cv.w};
#pragma unroll
            for (int i = 0; i < 4; i++)
#pragma unroll
                for (int j = 0; j < 4; j++) acc[i][j] = fmaf(bb[i], cc[j], acc[i][j]);
        }
#pragma unroll
        for (int i = 0; i < 4; i++)
            *(float4*)&G_T[ty * 4 + i][tx * 4] = make_float4(acc[i][0], acc[i][1], acc[i][2], acc[i][3]);
    }

    for (int h = 0; h < NHEADS; h++) {
        __syncthreads();   // previous head's readers done (also covers G_T store for h=0)
        for (int idx = tid; idx < 1024; idx += 256) {
            int s = idx >> 4, q = idx & 15;
            int tg = tglob(d, c, s);
            float4 v = *(const float4*)(xbc + (size_t)(b * SEQLEN + tg) * CONV_DIM + h * 64 + q * 4);
            *(float4*)&Xs[s][q * 4] = v;
        }
        if (tid < 64) {
            int flat = ((d * 4 + b) * 16 + h) * 32 + c;
            cum_l[tid] = cum_tab[(size_t)flat * 64 + tid];
            dtv_l[tid] = dtv_tab[(size_t)flat * 64 + tid];
        }
        __syncthreads();
        // M_T[s][t] = G_T[s][t] * exp(cum_t - cum_s) * dtv_s  for s<=t
#pragma unroll
        for (int i = 0; i < 4; i++) {
            int s = ty * 4 + i;
            float4 g = *(const float4*)&G_T[s][tx * 4];
            float gg[4] = {g.x, g.y, g.z, g.w};
            float cs = cum_l[s], dv = dtv_l[s];
            float4 m;
            float* mp = (float*)&m;
#pragma unroll
            for (int j = 0; j < 4; j++) {
                int t = tx * 4 + j;
                mp[j] = (s <= t) ? gg[j] * expf(cum_l[t] - cs) * dv : 0.f;
            }
            *(float4*)&M_T[s][tx * 4] = m;
        }
        __syncthreads();
        // Y[t][p] = sum_s M_T[s][t] * Xs[s][p]
        float acc[4][4] = {};
        for (int s = 0; s < 64; s++) {
            float4 mv = *(const float4*)&M_T[s][ty * 4];
            float4 xv = *(const float4*)&Xs[s][tx * 4];
            float mm[4] = {mv.x, mv.y, mv.z, mv.w};
            float xx[4] = {xv.x, xv.y, xv.z, xv.w};
#pragma unroll
            for (int i = 0; i < 4; i++)
#pragma unroll
                for (int j = 0; j < 4; j++) acc[i][j] = fmaf(mm[i], xx[j], acc[i][j]);
        }
#pragma unroll
        for (int i = 0; i < 4; i++) {
            int tl = ty * 4 + i;
            int tg = tglob(d, c, tl);
            int tout = d ? (tg - 1) : (tg + 1);
            if (tout >= 0 && tout < SEQLEN) {
                float* yp = y_sum + (size_t)(b * SEQLEN + tout) * D_INNER + h * 64 + tx * 4;
#pragma unroll
                for (int j = 0; j < 4; j++) unsafeAtomicAdd(yp + j, acc[i][j]);
            }
        }
    }
}

// ---------------- K2: per-chunk state S_T[n][p] (block = (d,b,h,chunk)) ----------------
__global__ __launch_bounds__(256) void ssd_state_kernel(const float* __restrict__ xbc,
                                                        const float* __restrict__ cum_tab,
                                                        const float* __restrict__ dtv_tab,
                                                        float* __restrict__ ws0)
{
    const int flat = blockIdx.x;
    const int c = flat & 31, h = (flat >> 5) & 15, b = (flat >> 9) & 3, d = flat >> 11;
    const int tid = threadIdx.x;
    const int ty = tid >> 4, tx = tid & 15;

    __shared__ float Bm[64][64];
    __shared__ float Xw[64][64];
    __shared__ float cum_l[64], dtv_l[64];

    if (tid < 64) {
        cum_l[tid] = cum_tab[(size_t)flat * 64 + tid];
        dtv_l[tid] = dtv_tab[(size_t)flat * 64 + tid];
    }
    __syncthreads();
    float clast = cum_l[63];
    for (int idx = tid; idx < 1024; idx += 256) {
        int s = idx >> 4, q = idx & 15;
        int tg = tglob(d, c, s);
        const float* row = xbc + (size_t)(b * SEQLEN + tg) * CONV_DIM;
        float4 vb = *(const float4*)(row + 1024 + q * 4);
        float4 vx = *(const float4*)(row + h * 64 + q * 4);
        float w = expf(clast - cum_l[s]) * dtv_l[s];
        vx.x *= w; vx.y *= w; vx.z *= w; vx.w *= w;
        *(float4*)&Bm[s][q * 4] = vb;
        *(float4*)&Xw[s][q * 4] = vx;
    }
    __syncthreads();
    // S_T[n][p] = sum_s Bm[s][n] * Xw[s][p]
    float acc[4][4] = {};
    for (int s = 0; s < 64; s++) {
        float4 bv = *(const float4*)&Bm[s][ty * 4];
        float4 xv = *(const float4*)&Xw[s][tx * 4];
        float bb[4] = {bv.x, bv.y, bv.z, bv.w};
        float xx[4] = {xv.x, xv.y, xv.z, xv.w};
#pragma unroll
        for (int i = 0; i < 4; i++)
#pragma unroll
            for (int j = 0; j < 4; j++) acc[i][j] = fmaf(bb[i], xx[j], acc[i][j]);
    }
    float* st = s_tile(ws0, flat);
#pragma unroll
    for (int i = 0; i < 4; i++)
        *(float4*)&st[(size_t)(ty * 4 + i) * 64 + tx * 4] =
            make_float4(acc[i][0], acc[i][1], acc[i][2], acc[i][3]);
}

// ---------------- K3: serial chunk scan, h_in[c] written in-place over S ----------------
__global__ __launch_bounds__(256) void ssd_chunkscan_kernel(const float* __restrict__ cum_tab,
                                                            float* __restrict__ ws0)
{
    const int g = blockIdx.x;           // (d,b,h)
    const int tid = threadIdx.x;
    const int base = g * 32;
    float4 hr[4] = {make_float4(0,0,0,0), make_float4(0,0,0,0), make_float4(0,0,0,0), make_float4(0,0,0,0)};
    for (int c = 0; c < 32; c++) {
        int flat = base + c;
        float dec = expf(cum_tab[(size_t)flat * 64 + 63]);
        float* Sp = s_tile(ws0, flat) + tid * 16;
        float4 s0 = *(float4*)(Sp + 0);
        float4 s1 = *(float4*)(Sp + 4);
        float4 s2 = *(float4*)(Sp + 8);
        float4 s3 = *(float4*)(Sp + 12);
        *(float4*)(Sp + 0) = hr[0];
        *(float4*)(Sp + 4) = hr[1];
        *(float4*)(Sp + 8) = hr[2];
        *(float4*)(Sp + 12) = hr[3];
        hr[0].x = hr[0].x * dec + s0.x; hr[0].y = hr[0].y * dec + s0.y; hr[0].z = hr[0].z * dec + s0.z; hr[0].w = hr[0].w * dec + s0.w;
        hr[1].x = hr[1].x * dec + s1.x; hr[1].y = hr[1].y * dec + s1.y; hr[1].z = hr[1].z * dec + s1.z; hr[1].w = hr[1].w * dec + s1.w;
        hr[2].x = hr[2].x * dec + s2.x; hr[2].y = hr[2].y * dec + s2.y; hr[2].z = hr[2].z * dec + s2.z; hr[2].w = hr[2].w * dec + s2.w;
        hr[3].x = hr[3].x * dec + s3.x; hr[3].y = hr[3].y * dec + s3.y; hr[3].z = hr[3].z * dec + s3.z; hr[3].w = hr[3].w * dec + s3.w;
    }
}

// ---------------- K4: inter-chunk Y += a_t * C_t . h_in (block = (d,b,h,chunk)) ----------------
__global__ __launch_bounds__(256) void ssd_inter_kernel(const float* __restrict__ xbc,
                                                        const float* __restrict__ cum_tab,
                                                        float* __restrict__ ws0,
                                                        float* __restrict__ y_sum)
{
    const int flat = blockIdx.x;
    const int c = flat & 31;
    if (c == 0) return;                 // h_in = 0
    const int h = (flat >> 5) & 15, b = (flat >> 9) & 3, d = flat >> 11;
    const int tid = threadIdx.x;
    const int ty = tid >> 4, tx = tid & 15;

    __shared__ float C_T[64][68];
    __shared__ float h_T[64][64];       // [n][p]
    __shared__ float cum_l[64];

    if (tid < 64) cum_l[tid] = cum_tab[(size_t)flat * 64 + tid];
    {
        const float* st = s_tile(ws0, flat);
        for (int idx = tid; idx < 1024; idx += 256) {
            int n = idx >> 4, q = idx & 15;
            *(float4*)&h_T[n][q * 4] = *(const float4*)(st + (size_t)n * 64 + q * 4);
        }
    }
    for (int idx = tid; idx < 1024; idx += 256) {
        int s = idx >> 4, q = idx & 15;
        int tg = tglob(d, c, s);
        float4 vc = *(const float4*)(xbc + (size_t)(b * SEQLEN + tg) * CONV_DIM + 1088 + q * 4);
        C_T[q*4+0][s] = vc.x; C_T[q*4+1][s] = vc.y; C_T[q*4+2][s] = vc.z; C_T[q*4+3][s] = vc.w;
    }
    __syncthreads();
    float acc[4][4] = {};
    for (int n = 0; n < 64; n++) {
        float4 cv = *(const float4*)&C_T[n][ty * 4];
        float4 hv = *(const float4*)&h_T[n][tx * 4];
        float cc[4] = {cv.x, cv.y, cv.z, cv.w};
        float hh[4] = {hv.x, hv.y, hv.z, hv.w};
#pragma unroll
        for (int i = 0; i < 4; i++)
#pragma unroll
            for (int j = 0; j < 4; j++) acc[i][j] = fmaf(cc[i], hh[j], acc[i][j]);
    }
#pragma unroll
    for (int i = 0; i < 4; i++) {
        int tl = ty * 4 + i;
        float a = expf(cum_l[tl]);
        int tg = tglob(d, c, tl);
        int tout = d ? (tg - 1) : (tg + 1);
        if (tout >= 0 && tout < SEQLEN) {
            float* yp = y_sum + (size_t)(b * SEQLEN + tout) * D_INNER + h * 64 + tx * 4;
#pragma unroll
            for (int j = 0; j < 4; j++) unsafeAtomicAdd(yp + j, acc[i][j] * a);
        }
    }
}

// ---------------- combine: (y + xs*Dp)*silu(z), RMSNorm -> in-place y ----------------
__global__ __launch_bounds__(256) void combine_kernel(const float* __restrict__ zxbcdt,
                                                      const float* __restrict__ xbc,
                                                      const float* __restrict__ Dp,
                                                      const float* __restrict__ rms_w,
                                                      float* __restrict__ yg)
{
    int row = blockIdx.x;
    int i = threadIdx.x * 4;
    float4 ys = *(const float4*)(yg + (size_t)row * D_INNER + i);
    float4 xs = *(const float4*)(xbc + (size_t)row * CONV_DIM + i);
    float4 z  = *(const float4*)(zxbcdt + (size_t)row * D_IN_PROJ + i);
    float dp = Dp[i >> 6];
    float g[4];
    g[0] = (ys.x + xs.x * dp) * siluf(z.x);
    g[1] = (ys.y + xs.y * dp) * siluf(z.y);
    g[2] = (ys.z + xs.z * dp) * siluf(z.z);
    g[3] = (ys.w + xs.w * dp) * siluf(z.w);
    float ss = g[0]*g[0] + g[1]*g[1] + g[2]*g[2] + g[3]*g[3];
#pragma unroll
    for (int m = 1; m < 64; m <<= 1) ss += __shfl_xor(ss, m, 64);
    __shared__ float red[4];
    if ((threadIdx.x & 63) == 0) red[threadIdx.x >> 6] = ss;
    __syncthreads();
    ss = red[0] + red[1] + red[2] + red[3];
    float scale = rsqrtf(ss * (1.f / D_INNER) + EPS);
    float4 rw = *(const float4*)(rms_w + i);
    float4 o;
    o.x = g[0] * scale * rw.x; o.y = g[1] * scale * rw.y;
    o.z = g[2] * scale * rw.z; o.w = g[3] * scale * rw.w;
    *(float4*)(yg + (size_t)row * D_INNER + i) = o;
}

// ---------------- launch ----------------
extern "C" void kernel_launch(void* const* d_in, const int* in_sizes, int n_in,
                              void* d_out, int out_size, void* d_ws, size_t ws_size,
                              hipStream_t stream)
{
    const float* x         = (const float*)d_in[0];
    const float* ln1_w     = (const float*)d_in[1];
    const float* ln1_b     = (const float*)d_in[2];
    const float* in_proj_w = (const float*)d_in[3];
    const float* conv_w    = (const float*)d_in[4];
    const float* conv_b    = (const float*)d_in[5];
    const float* dt_bias   = (const float*)d_in[6];
    const float* A_log     = (const float*)d_in[7];
    const float* Dp        = (const float*)d_in[8];
    const float* rms_w     = (const float*)d_in[9];
    const float* out_proj_w= (const float*)d_in[10];
    const float* ln2_w     = (const float*)d_in[11];
    const float* ln2_b     = (const float*)d_in[12];
    const float* fc1_w     = (const float*)d_in[13];
    const float* fc1_b     = (const float*)d_in[14];
    const float* fc2_w     = (const float*)d_in[15];
    const float* fc2_b     = (const float*)d_in[16];
    float* out = (float*)d_out;

    float* ws0    = (float*)d_ws;
    float* buf_h  = ws0;
    float* zxbcdt = ws0 + OFF_ZX;
    float* xbc    = ws0 + OFF_XBC;
    float* y_sum  = ws0 + OFF_YSUM;
    float* x_res  = ws0 + OFF_S2;          // reused after scan consumes S tiles
    float* f1     = zxbcdt;
    float* cum_tab = out;                   // d_out scratch (overwritten by fc2)
    float* dtv_tab = out + 262144;

    ln_kernel<<<dim3(NTOK / 4), dim3(256), 0, stream>>>(x, ln1_w, ln1_b, buf_h, NTOK);
    gemm_nt<<<dim3((D_IN_PROJ + BN - 1) / BN, NTOK / BM), dim3(256), 0, stream>>>(
        buf_h, in_proj_w, zxbcdt, NTOK, D_IN_PROJ, D_MODEL, nullptr, nullptr, 0);
    conv_kernel<<<dim3(NTOK * CONV_DIM / 256), dim3(256), 0, stream>>>(zxbcdt, conv_w, conv_b, xbc);

    dt_table_kernel<<<dim3(1024), dim3(256), 0, stream>>>(zxbcdt, dt_bias, A_log, cum_tab, dtv_tab);
    zero_kernel<<<dim3(8192), dim3(256), 0, stream>>>((float4*)y_sum, NTOK * D_INNER / 4);
    ssd_intra_kernel<<<dim3(256), dim3(256), 0, stream>>>(xbc, cum_tab, dtv_tab, y_sum);
    ssd_state_kernel<<<dim3(4096), dim3(256), 0, stream>>>(xbc, cum_tab, dtv_tab, ws0);
    ssd_chunkscan_kernel<<<dim3(128), dim3(256), 0, stream>>>(cum_tab, ws0);
    ssd_inter_kernel<<<dim3(4096), dim3(256), 0, stream>>>(xbc, cum_tab, ws0, y_sum);

    combine_kernel<<<dim3(NTOK), dim3(256), 0, stream>>>(zxbcdt, xbc, Dp, rms_w, y_sum);
    gemm_nt<<<dim3(D_MODEL / BN, NTOK / BM), dim3(256), 0, stream>>>(
        y_sum, out_proj_w, x_res, NTOK, D_MODEL, D_INNER, nullptr, x, 0);
    ln_kernel<<<dim3(NTOK / 4), dim3(256), 0, stream>>>(x_res, ln2_w, ln2_b, buf_h, NTOK);
    gemm_nt<<<dim3(D_FF / BN, NTOK / BM), dim3(256), 0, stream>>>(
        buf_h, fc1_w, f1, NTOK, D_FF, D_MODEL, fc1_b, nullptr, 1);
    gemm_nt<<<dim3(D_MODEL / BN, NTOK / BM), dim3(256), 0, stream>>>(
        f1, fc2_w, out, NTOK, D_MODEL, D_FF, fc2_b, x_res, 0);
}

// Round 3
// 928.154 us; speedup vs baseline: 1.7265x; 1.6822x over previous
//
#include <hip/hip_runtime.h>
#include <math.h>

#define D_MODEL   512
#define D_INNER   1024
#define NHEADS    16
#define HEADDIM   64
#define D_STATE   64
#define D_CONV    7
#define D_FF      2048
#define CONV_DIM  1152
#define D_IN_PROJ 2208
#define BATCH     4
#define SEQLEN    2048
#define NTOK      (BATCH*SEQLEN)
#define EPS       1e-5f

// ---- workspace layout (float units) ----
// zxbcdt : [0, 18087936)                 8192x2208 fp32   (later f1_bf overlays as ushort)
// xbc    : [18087936, 27525120)          8192x1152 fp32
// y_sum  : [27525120, 35913728)          8192x1024 fp32
// sreg   : [35913728, 52690944)          16.77M floats: S-tiles during scan; before/after:
//   hA_bf  = sreg[0 .. 2097152)          bf16 8192x512 (ln1/ln2 out)
//   P      = sreg[2097152 .. 2686976)    bf16 weight pad buffer (max 2304x512)
//   yg_bf  = sreg[2686976 .. 4784128)    bf16 8192x1024
//   x_res  = sreg[4784128 .. 8978432)    fp32 8192x512
#define OFF_XBC   18087936ull
#define OFF_YSUM  27525120ull
#define OFF_SREG  35913728ull

typedef __bf16 bf16x8 __attribute__((ext_vector_type(8)));
typedef float  f32x4  __attribute__((ext_vector_type(4)));

__device__ __forceinline__ float siluf(float x) { return x / (1.f + expf(-x)); }
__device__ __forceinline__ float geluf(float x) { return 0.5f * x * (1.f + erff(x * 0.70710678118654752f)); }
__device__ __forceinline__ float softplusf(float x) { return fmaxf(x, 0.f) + log1pf(expf(-fabsf(x))); }
__device__ __forceinline__ int tglob(int d, int c, int t) { int s = c * 64 + t; return d ? (SEQLEN - 1 - s) : s; }
__device__ __forceinline__ unsigned short f2bf(float f) {
    unsigned int u = __float_as_uint(f);
    u += 0x7FFFu + ((u >> 16) & 1u);
    return (unsigned short)(u >> 16);
}
__device__ __forceinline__ void glds16(const void* g, void* l) {
    __builtin_amdgcn_global_load_lds((const __attribute__((address_space(1))) void*)g,
                                     (__attribute__((address_space(3))) void*)l, 16, 0, 0);
}

// ---------------- LayerNorm -> bf16 ----------------
__global__ __launch_bounds__(256) void ln_kernel(const float* __restrict__ x,
                                                 const float* __restrict__ w,
                                                 const float* __restrict__ b,
                                                 unsigned short* __restrict__ out, int nrows)
{
    int wid = threadIdx.x >> 6;
    int lane = threadIdx.x & 63;
    int row = blockIdx.x * 4 + wid;
    if (row >= nrows) return;
    const float* xr = x + (size_t)row * D_MODEL;
    float4 v0 = *(const float4*)(xr + lane * 8);
    float4 v1 = *(const float4*)(xr + lane * 8 + 4);
    float v[8] = {v0.x, v0.y, v0.z, v0.w, v1.x, v1.y, v1.z, v1.w};
    float s = 0.f;
#pragma unroll
    for (int i = 0; i < 8; i++) s += v[i];
#pragma unroll
    for (int m = 1; m < 64; m <<= 1) s += __shfl_xor(s, m, 64);
    float mu = s * (1.f / D_MODEL);
    float q = 0.f;
#pragma unroll
    for (int i = 0; i < 8; i++) { float dd = v[i] - mu; q += dd * dd; }
#pragma unroll
    for (int m = 1; m < 64; m <<= 1) q += __shfl_xor(q, m, 64);
    float inv = rsqrtf(q * (1.f / D_MODEL) + EPS);
    float4 w0 = *(const float4*)(w + lane * 8);
    float4 w1 = *(const float4*)(w + lane * 8 + 4);
    float4 b0 = *(const float4*)(b + lane * 8);
    float4 b1 = *(const float4*)(b + lane * 8 + 4);
    float o[8];
    o[0] = (v[0]-mu)*inv*w0.x + b0.x; o[1] = (v[1]-mu)*inv*w0.y + b0.y;
    o[2] = (v[2]-mu)*inv*w0.z + b0.z; o[3] = (v[3]-mu)*inv*w0.w + b0.w;
    o[4] = (v[4]-mu)*inv*w1.x + b1.x; o[5] = (v[5]-mu)*inv*w1.y + b1.y;
    o[6] = (v[6]-mu)*inv*w1.z + b1.z; o[7] = (v[7]-mu)*inv*w1.w + b1.w;
    unsigned short* orow = out + (size_t)row * D_MODEL + lane * 8;
    ushort4 p0, p1;
    p0.x = f2bf(o[0]); p0.y = f2bf(o[1]); p0.z = f2bf(o[2]); p0.w = f2bf(o[3]);
    p1.x = f2bf(o[4]); p1.y = f2bf(o[5]); p1.z = f2bf(o[6]); p1.w = f2bf(o[7]);
    *(ushort4*)orow = p0;
    *(ushort4*)(orow + 4) = p1;
}

// ---------------- weight fp32 -> bf16 (zero-pad to dst_n) ----------------
__global__ __launch_bounds__(256) void wconv_kernel(const float* __restrict__ src,
                                                    unsigned short* __restrict__ dst,
                                                    int src_n, int dst_n)
{
    int i = (blockIdx.x * 256 + threadIdx.x) * 4;
    if (i >= dst_n) return;
    ushort4 o;
    if (i < src_n) {
        float4 v = *(const float4*)(src + i);
        o.x = f2bf(v.x); o.y = f2bf(v.y); o.z = f2bf(v.z); o.w = f2bf(v.w);
    } else {
        o.x = o.y = o.z = o.w = 0;
    }
    *(ushort4*)(dst + i) = o;
}

// ---------------- bf16 MFMA GEMM: C[M,Nreal] = A[M,K] @ W[N,K]^T ----------------
// m97 structure: 128x128 tile, 4 waves (2x2 of 64x64), 16x16x32 MFMA, global_load_lds w=16.
__global__ __launch_bounds__(256, 2) void gemm_bf16(const unsigned short* __restrict__ A,
                                                    const unsigned short* __restrict__ W,
                                                    int K, int Nreal,
                                                    float* __restrict__ Cf,
                                                    unsigned short* __restrict__ Cb,
                                                    const float* __restrict__ bias,
                                                    const float* __restrict__ res, int act)
{
    __shared__ unsigned short As[128 * 32];
    __shared__ unsigned short Ws[128 * 32];
    const int tid = threadIdx.x;
    const int wave = tid >> 6;
    const int lane = tid & 63;
    const int m0 = blockIdx.y * 128;
    const int n0 = blockIdx.x * 128;
    const int wm = (wave & 1) * 64;
    const int wn = (wave >> 1) * 64;

    // staging: each wave issues 2 A + 2 W 16B direct-to-LDS loads per K-tile
    const size_t gA = (size_t)(m0 + 32 * wave + (lane >> 2)) * K + (lane & 3) * 8;
    const size_t gW = (size_t)(n0 + 32 * wave + (lane >> 2)) * K + (lane & 3) * 8;
    unsigned short* lA = As + wave * 1024 + lane * 8;
    unsigned short* lW = Ws + wave * 1024 + lane * 8;

    const int fr = lane & 15;
    const int fq = (lane >> 4) * 8;
    f32x4 acc[4][4] = {};

    for (int k0 = 0; k0 < K; k0 += 32) {
        glds16(A + gA + k0, lA);
        glds16(A + gA + (size_t)16 * K + k0, lA + 512);
        glds16(W + gW + k0, lW);
        glds16(W + gW + (size_t)16 * K + k0, lW + 512);
        __syncthreads();
        bf16x8 af[4], bf[4];
#pragma unroll
        for (int mi = 0; mi < 4; mi++)
            af[mi] = *(const bf16x8*)(As + (wm + mi * 16 + fr) * 32 + fq);
#pragma unroll
        for (int ni = 0; ni < 4; ni++)
            bf[ni] = *(const bf16x8*)(Ws + (wn + ni * 16 + fr) * 32 + fq);
#pragma unroll
        for (int mi = 0; mi < 4; mi++)
#pragma unroll
            for (int ni = 0; ni < 4; ni++)
                acc[mi][ni] = __builtin_amdgcn_mfma_f32_16x16x32_bf16(af[mi], bf[ni], acc[mi][ni], 0, 0, 0);
        __syncthreads();
    }

    // epilogue: C/D layout col=lane&15, row=(lane>>4)*4+reg  [m89-verified]
    const int colb = n0 + wn + (lane & 15);
    const int rowb = m0 + wm + (lane >> 4) * 4;
#pragma unroll
    for (int mi = 0; mi < 4; mi++) {
#pragma unroll
        for (int ni = 0; ni < 4; ni++) {
            int col = colb + ni * 16;
            if (col < Nreal) {
#pragma unroll
                for (int r = 0; r < 4; r++) {
                    int row = rowb + mi * 16 + r;
                    float v = acc[mi][ni][r];
                    size_t idx = (size_t)row * Nreal + col;
                    if (bias) v += bias[col];
                    if (res) v += res[idx];
                    if (act) v = geluf(v);
                    if (Cb) Cb[idx] = f2bf(v);
                    else    Cf[idx] = v;
                }
            }
        }
    }
}

// ---------------- depthwise causal conv (k=7) + bias + SiLU ----------------
__global__ __launch_bounds__(256) void conv_kernel(const float* __restrict__ zxbcdt,
                                                   const float* __restrict__ conv_w,
                                                   const float* __restrict__ conv_b,
                                                   float* __restrict__ out)
{
    int gid = blockIdx.x * 256 + threadIdx.x;
    if (gid >= NTOK * CONV_DIM) return;
    int c = gid % CONV_DIM;
    int bt = gid / CONV_DIM;
    int t = bt & (SEQLEN - 1);
    float acc = conv_b[c];
    const float* base = zxbcdt + (size_t)bt * D_IN_PROJ + D_INNER + c;
#pragma unroll
    for (int j = 0; j < D_CONV; j++) {
        int tt = t - 6 + j;
        if (tt >= 0) acc = fmaf(conv_w[c * D_CONV + j], base[(ptrdiff_t)(j - 6) * D_IN_PROJ], acc);
    }
    out[(size_t)bt * CONV_DIM + c] = siluf(acc);
}

// ---------------- dt/cum tables ----------------
__global__ __launch_bounds__(256) void dt_table_kernel(const float* __restrict__ zxbcdt,
                                                       const float* __restrict__ dt_bias,
                                                       const float* __restrict__ A_log,
                                                       float* __restrict__ cum_tab,
                                                       float* __restrict__ dtv_tab)
{
    int wid = blockIdx.x * 4 + (threadIdx.x >> 6);
    int lane = threadIdx.x & 63;
    int c = wid & 31, h = (wid >> 5) & 15, b = (wid >> 9) & 3, d = wid >> 11;
    int tg = tglob(d, c, lane);
    float raw = zxbcdt[(size_t)(b * SEQLEN + tg) * D_IN_PROJ + 2176 + d * 16 + h] + dt_bias[h];
    float dtv = softplusf(raw);
    float cum = -expf(A_log[h]) * dtv;
#pragma unroll
    for (int off = 1; off < 64; off <<= 1) {
        int src = lane - off;
        float o = __shfl(cum, src < 0 ? 0 : src, 64);
        if (lane >= off) cum += o;
    }
    cum_tab[(size_t)wid * 64 + lane] = cum;
    dtv_tab[(size_t)wid * 64 + lane] = dtv;
}

__global__ __launch_bounds__(256) void zero_kernel(float4* __restrict__ p, int n4)
{
    int i = blockIdx.x * 256 + threadIdx.x;
    if (i < n4) p[i] = make_float4(0.f, 0.f, 0.f, 0.f);
}

// ---------------- K1: intra-chunk ----------------
__global__ __launch_bounds__(256) void ssd_intra_kernel(const float* __restrict__ xbc,
                                                        const float* __restrict__ cum_tab,
                                                        const float* __restrict__ dtv_tab,
                                                        float* __restrict__ y_sum)
{
    const int bid = blockIdx.x;
    const int c = bid & 31, b = (bid >> 5) & 3, d = bid >> 7;
    const int tid = threadIdx.x;
    const int ty = tid >> 4, tx = tid & 15;

    __shared__ float B_T[64][68];
    __shared__ float C_T[64][68];
    __shared__ float G_T[64][64];
    __shared__ float M_T[64][64];
    __shared__ float Xs[64][64];
    __shared__ float cum_l[64], dtv_l[64];

    for (int idx = tid; idx < 1024; idx += 256) {
        int s = idx >> 4, q = idx & 15;
        int tg = tglob(d, c, s);
        const float* row = xbc + (size_t)(b * SEQLEN + tg) * CONV_DIM;
        float4 vb = *(const float4*)(row + 1024 + q * 4);
        float4 vc = *(const float4*)(row + 1088 + q * 4);
        B_T[q*4+0][s] = vb.x; B_T[q*4+1][s] = vb.y; B_T[q*4+2][s] = vb.z; B_T[q*4+3][s] = vb.w;
        C_T[q*4+0][s] = vc.x; C_T[q*4+1][s] = vc.y; C_T[q*4+2][s] = vc.z; C_T[q*4+3][s] = vc.w;
    }
    __syncthreads();
    {
        float acc[4][4] = {};
        for (int n = 0; n < 64; n++) {
            float4 bv = *(const float4*)&B_T[n][ty * 4];
            float4 cv = *(const float4*)&C_T[n][tx * 4];
            float bb[4] = {bv.x, bv.y, bv.z, bv.w};
            float cc[4] = {cv.x, cv.y, cv.z, cv.w};
#pragma unroll
            for (int i = 0; i < 4; i++)
#pragma unroll
                for (int j = 0; j < 4; j++) acc[i][j] = fmaf(bb[i], cc[j], acc[i][j]);
        }
#pragma unroll
        for (int i = 0; i < 4; i++)
            *(float4*)&G_T[ty * 4 + i][tx * 4] = make_float4(acc[i][0], acc[i][1], acc[i][2], acc[i][3]);
    }

    for (int h = 0; h < NHEADS; h++) {
        __syncthreads();
        for (int idx = tid; idx < 1024; idx += 256) {
            int s = idx >> 4, q = idx & 15;
            int tg = tglob(d, c, s);
            float4 v = *(const float4*)(xbc + (size_t)(b * SEQLEN + tg) * CONV_DIM + h * 64 + q * 4);
            *(float4*)&Xs[s][q * 4] = v;
        }
        if (tid < 64) {
            int flat = ((d * 4 + b) * 16 + h) * 32 + c;
            cum_l[tid] = cum_tab[(size_t)flat * 64 + tid];
            dtv_l[tid] = dtv_tab[(size_t)flat * 64 + tid];
        }
        __syncthreads();
#pragma unroll
        for (int i = 0; i < 4; i++) {
            int s = ty * 4 + i;
            float4 g = *(const float4*)&G_T[s][tx * 4];
            float gg[4] = {g.x, g.y, g.z, g.w};
            float cs = cum_l[s], dv = dtv_l[s];
            float4 m;
            float* mp = (float*)&m;
#pragma unroll
            for (int j = 0; j < 4; j++) {
                int t = tx * 4 + j;
                mp[j] = (s <= t) ? gg[j] * expf(cum_l[t] - cs) * dv : 0.f;
            }
            *(float4*)&M_T[s][tx * 4] = m;
        }
        __syncthreads();
        float acc[4][4] = {};
        for (int s = 0; s < 64; s++) {
            float4 mv = *(const float4*)&M_T[s][ty * 4];
            float4 xv = *(const float4*)&Xs[s][tx * 4];
            float mm[4] = {mv.x, mv.y, mv.z, mv.w};
            float xx[4] = {xv.x, xv.y, xv.z, xv.w};
#pragma unroll
            for (int i = 0; i < 4; i++)
#pragma unroll
                for (int j = 0; j < 4; j++) acc[i][j] = fmaf(mm[i], xx[j], acc[i][j]);
        }
#pragma unroll
        for (int i = 0; i < 4; i++) {
            int tl = ty * 4 + i;
            int tg = tglob(d, c, tl);
            int tout = d ? (tg - 1) : (tg + 1);
            if (tout >= 0 && tout < SEQLEN) {
                float* yp = y_sum + (size_t)(b * SEQLEN + tout) * D_INNER + h * 64 + tx * 4;
#pragma unroll
                for (int j = 0; j < 4; j++) unsafeAtomicAdd(yp + j, acc[i][j]);
            }
        }
    }
}

// ---------------- K2: per-chunk state ----------------
__global__ __launch_bounds__(256) void ssd_state_kernel(const float* __restrict__ xbc,
                                                        const float* __restrict__ cum_tab,
                                                        const float* __restrict__ dtv_tab,
                                                        float* __restrict__ sreg)
{
    const int flat = blockIdx.x;
    const int c = flat & 31, h = (flat >> 5) & 15, b = (flat >> 9) & 3, d = flat >> 11;
    const int tid = threadIdx.x;
    const int ty = tid >> 4, tx = tid & 15;

    __shared__ float Bm[64][64];
    __shared__ float Xw[64][64];
    __shared__ float cum_l[64], dtv_l[64];

    if (tid < 64) {
        cum_l[tid] = cum_tab[(size_t)flat * 64 + tid];
        dtv_l[tid] = dtv_tab[(size_t)flat * 64 + tid];
    }
    __syncthreads();
    float clast = cum_l[63];
    for (int idx = tid; idx < 1024; idx += 256) {
        int s = idx >> 4, q = idx & 15;
        int tg = tglob(d, c, s);
        const float* row = xbc + (size_t)(b * SEQLEN + tg) * CONV_DIM;
        float4 vb = *(const float4*)(row + 1024 + q * 4);
        float4 vx = *(const float4*)(row + h * 64 + q * 4);
        float w = expf(clast - cum_l[s]) * dtv_l[s];
        vx.x *= w; vx.y *= w; vx.z *= w; vx.w *= w;
        *(float4*)&Bm[s][q * 4] = vb;
        *(float4*)&Xw[s][q * 4] = vx;
    }
    __syncthreads();
    float acc[4][4] = {};
    for (int s = 0; s < 64; s++) {
        float4 bv = *(const float4*)&Bm[s][ty * 4];
        float4 xv = *(const float4*)&Xw[s][tx * 4];
        float bb[4] = {bv.x, bv.y, bv.z, bv.w};
        float xx[4] = {xv.x, xv.y, xv.z, xv.w};
#pragma unroll
        for (int i = 0; i < 4; i++)
#pragma unroll
            for (int j = 0; j < 4; j++) acc[i][j] = fmaf(bb[i], xx[j], acc[i][j]);
    }
    float* st = sreg + (size_t)flat * 4096;
#pragma unroll
    for (int i = 0; i < 4; i++)
        *(float4*)&st[(size_t)(ty * 4 + i) * 64 + tx * 4] =
            make_float4(acc[i][0], acc[i][1], acc[i][2], acc[i][3]);
}

// ---------------- K3: serial chunk scan ----------------
__global__ __launch_bounds__(256) void ssd_chunkscan_kernel(const float* __restrict__ cum_tab,
                                                            float* __restrict__ sreg)
{
    const int g = blockIdx.x;
    const int tid = threadIdx.x;
    const int base = g * 32;
    float4 hr[4] = {make_float4(0,0,0,0), make_float4(0,0,0,0), make_float4(0,0,0,0), make_float4(0,0,0,0)};
    for (int c = 0; c < 32; c++) {
        int flat = base + c;
        float dec = expf(cum_tab[(size_t)flat * 64 + 63]);
        float* Sp = sreg + (size_t)flat * 4096 + tid * 16;
        float4 s0 = *(float4*)(Sp + 0);
        float4 s1 = *(float4*)(Sp + 4);
        float4 s2 = *(float4*)(Sp + 8);
        float4 s3 = *(float4*)(Sp + 12);
        *(float4*)(Sp + 0) = hr[0];
        *(float4*)(Sp + 4) = hr[1];
        *(float4*)(Sp + 8) = hr[2];
        *(float4*)(Sp + 12) = hr[3];
        hr[0].x = hr[0].x * dec + s0.x; hr[0].y = hr[0].y * dec + s0.y; hr[0].z = hr[0].z * dec + s0.z; hr[0].w = hr[0].w * dec + s0.w;
        hr[1].x = hr[1].x * dec + s1.x; hr[1].y = hr[1].y * dec + s1.y; hr[1].z = hr[1].z * dec + s1.z; hr[1].w = hr[1].w * dec + s1.w;
        hr[2].x = hr[2].x * dec + s2.x; hr[2].y = hr[2].y * dec + s2.y; hr[2].z = hr[2].z * dec + s2.z; hr[2].w = hr[2].w * dec + s2.w;
        hr[3].x = hr[3].x * dec + s3.x; hr[3].y = hr[3].y * dec + s3.y; hr[3].z = hr[3].z * dec + s3.z; hr[3].w = hr[3].w * dec + s3.w;
    }
}

// ---------------- K4: inter-chunk ----------------
__global__ __launch_bounds__(256) void ssd_inter_kernel(const float* __restrict__ xbc,
                                                        const float* __restrict__ cum_tab,
                                                        float* __restrict__ sreg,
                                                        float* __restrict__ y_sum)
{
    const int flat = blockIdx.x;
    const int c = flat & 31;
    if (c == 0) return;
    const int h = (flat >> 5) & 15, b = (flat >> 9) & 3, d = flat >> 11;
    const int tid = threadIdx.x;
    const int ty = tid >> 4, tx = tid & 15;

    __shared__ float C_T[64][68];
    __shared__ float h_T[64][64];
    __shared__ float cum_l[64];

    if (tid < 64) cum_l[tid] = cum_tab[(size_t)flat * 64 + tid];
    {
        const float* st = sreg + (size_t)flat * 4096;
        for (int idx = tid; idx < 1024; idx += 256) {
            int n = idx >> 4, q = idx & 15;
            *(float4*)&h_T[n][q * 4] = *(const float4*)(st + (size_t)n * 64 + q * 4);
        }
    }
    for (int idx = tid; idx < 1024; idx += 256) {
        int s = idx >> 4, q = idx & 15;
        int tg = tglob(d, c, s);
        float4 vc = *(const float4*)(xbc + (size_t)(b * SEQLEN + tg) * CONV_DIM + 1088 + q * 4);
        C_T[q*4+0][s] = vc.x; C_T[q*4+1][s] = vc.y; C_T[q*4+2][s] = vc.z; C_T[q*4+3][s] = vc.w;
    }
    __syncthreads();
    float acc[4][4] = {};
    for (int n = 0; n < 64; n++) {
        float4 cv = *(const float4*)&C_T[n][ty * 4];
        float4 hv = *(const float4*)&h_T[n][tx * 4];
        float cc[4] = {cv.x, cv.y, cv.z, cv.w};
        float hh[4] = {hv.x, hv.y, hv.z, hv.w};
#pragma unroll
        for (int i = 0; i < 4; i++)
#pragma unroll
            for (int j = 0; j < 4; j++) acc[i][j] = fmaf(cc[i], hh[j], acc[i][j]);
    }
#pragma unroll
    for (int i = 0; i < 4; i++) {
        int tl = ty * 4 + i;
        float a = expf(cum_l[tl]);
        int tg = tglob(d, c, tl);
        int tout = d ? (tg - 1) : (tg + 1);
        if (tout >= 0 && tout < SEQLEN) {
            float* yp = y_sum + (size_t)(b * SEQLEN + tout) * D_INNER + h * 64 + tx * 4;
#pragma unroll
            for (int j = 0; j < 4; j++) unsafeAtomicAdd(yp + j, acc[i][j] * a);
        }
    }
}

// ---------------- combine -> bf16 yg ----------------
__global__ __launch_bounds__(256) void combine_kernel(const float* __restrict__ zxbcdt,
                                                      const float* __restrict__ xbc,
                                                      const float* __restrict__ y_sum,
                                                      const float* __restrict__ Dp,
                                                      const float* __restrict__ rms_w,
                                                      unsigned short* __restrict__ yg)
{
    int row = blockIdx.x;
    int i = threadIdx.x * 4;
    float4 ys = *(const float4*)(y_sum + (size_t)row * D_INNER + i);
    float4 xs = *(const float4*)(xbc + (size_t)row * CONV_DIM + i);
    float4 z  = *(const float4*)(zxbcdt + (size_t)row * D_IN_PROJ + i);
    float dp = Dp[i >> 6];
    float g[4];
    g[0] = (ys.x + xs.x * dp) * siluf(z.x);
    g[1] = (ys.y + xs.y * dp) * siluf(z.y);
    g[2] = (ys.z + xs.z * dp) * siluf(z.z);
    g[3] = (ys.w + xs.w * dp) * siluf(z.w);
    float ss = g[0]*g[0] + g[1]*g[1] + g[2]*g[2] + g[3]*g[3];
#pragma unroll
    for (int m = 1; m < 64; m <<= 1) ss += __shfl_xor(ss, m, 64);
    __shared__ float red[4];
    if ((threadIdx.x & 63) == 0) red[threadIdx.x >> 6] = ss;
    __syncthreads();
    ss = red[0] + red[1] + red[2] + red[3];
    float scale = rsqrtf(ss * (1.f / D_INNER) + EPS);
    float4 rw = *(const float4*)(rms_w + i);
    ushort4 o;
    o.x = f2bf(g[0] * scale * rw.x); o.y = f2bf(g[1] * scale * rw.y);
    o.z = f2bf(g[2] * scale * rw.z); o.w = f2bf(g[3] * scale * rw.w);
    *(ushort4*)(yg + (size_t)row * D_INNER + i) = o;
}

// ---------------- launch ----------------
extern "C" void kernel_launch(void* const* d_in, const int* in_sizes, int n_in,
                              void* d_out, int out_size, void* d_ws, size_t ws_size,
                              hipStream_t stream)
{
    const float* x         = (const float*)d_in[0];
    const float* ln1_w     = (const float*)d_in[1];
    const float* ln1_b     = (const float*)d_in[2];
    const float* in_proj_w = (const float*)d_in[3];
    const float* conv_w    = (const float*)d_in[4];
    const float* conv_b    = (const float*)d_in[5];
    const float* dt_bias   = (const float*)d_in[6];
    const float* A_log     = (const float*)d_in[7];
    const float* Dp        = (const float*)d_in[8];
    const float* rms_w     = (const float*)d_in[9];
    const float* out_proj_w= (const float*)d_in[10];
    const float* ln2_w     = (const float*)d_in[11];
    const float* ln2_b     = (const float*)d_in[12];
    const float* fc1_w     = (const float*)d_in[13];
    const float* fc1_b     = (const float*)d_in[14];
    const float* fc2_w     = (const float*)d_in[15];
    const float* fc2_b     = (const float*)d_in[16];
    float* out = (float*)d_out;

    float* ws0    = (float*)d_ws;
    float* zxbcdt = ws0;
    float* xbc    = ws0 + OFF_XBC;
    float* y_sum  = ws0 + OFF_YSUM;
    float* sreg   = ws0 + OFF_SREG;
    unsigned short* hA_bf = (unsigned short*)sreg;                     // 8192x512 bf16
    unsigned short* P     = (unsigned short*)(sreg + 2097152);         // weight pad buf
    unsigned short* yg_bf = (unsigned short*)(sreg + 2686976);         // 8192x1024 bf16
    float* x_res          = sreg + 4784128;                            // 8192x512 fp32
    unsigned short* f1_bf = (unsigned short*)zxbcdt;                   // 8192x2048 bf16 overlay
    float* cum_tab = out;                                              // d_out scratch
    float* dtv_tab = out + 262144;

    // 1. LN1 -> bf16
    ln_kernel<<<dim3(NTOK / 4), dim3(256), 0, stream>>>(x, ln1_w, ln1_b, hA_bf, NTOK);
    // 2. in_proj (N padded 2208->2304)
    wconv_kernel<<<dim3(2304 * 512 / 1024), dim3(256), 0, stream>>>(in_proj_w, P, 2208 * 512, 2304 * 512);
    gemm_bf16<<<dim3(18, 64), dim3(256), 0, stream>>>(hA_bf, P, 512, 2208, zxbcdt, nullptr, nullptr, nullptr, 0);
    // 3. conv
    conv_kernel<<<dim3(NTOK * CONV_DIM / 256), dim3(256), 0, stream>>>(zxbcdt, conv_w, conv_b, xbc);
    // 4. SSD
    dt_table_kernel<<<dim3(1024), dim3(256), 0, stream>>>(zxbcdt, dt_bias, A_log, cum_tab, dtv_tab);
    zero_kernel<<<dim3(8192), dim3(256), 0, stream>>>((float4*)y_sum, NTOK * D_INNER / 4);
    ssd_intra_kernel<<<dim3(256), dim3(256), 0, stream>>>(xbc, cum_tab, dtv_tab, y_sum);
    ssd_state_kernel<<<dim3(4096), dim3(256), 0, stream>>>(xbc, cum_tab, dtv_tab, sreg);
    ssd_chunkscan_kernel<<<dim3(128), dim3(256), 0, stream>>>(cum_tab, sreg);
    ssd_inter_kernel<<<dim3(4096), dim3(256), 0, stream>>>(xbc, cum_tab, sreg, y_sum);
    // 5. combine -> bf16 yg
    combine_kernel<<<dim3(NTOK), dim3(256), 0, stream>>>(zxbcdt, xbc, y_sum, Dp, rms_w, yg_bf);
    // 6. out_proj + residual(x)
    wconv_kernel<<<dim3(512 * 1024 / 1024), dim3(256), 0, stream>>>(out_proj_w, P, 512 * 1024, 512 * 1024);
    gemm_bf16<<<dim3(4, 64), dim3(256), 0, stream>>>(yg_bf, P, 1024, 512, x_res, nullptr, nullptr, x, 0);
    // 7. LN2 -> bf16
    ln_kernel<<<dim3(NTOK / 4), dim3(256), 0, stream>>>(x_res, ln2_w, ln2_b, hA_bf, NTOK);
    // 8. fc1 + bias + GELU -> bf16
    wconv_kernel<<<dim3(2048 * 512 / 1024), dim3(256), 0, stream>>>(fc1_w, P, 2048 * 512, 2048 * 512);
    gemm_bf16<<<dim3(16, 64), dim3(256), 0, stream>>>(hA_bf, P, 512, 2048, nullptr, f1_bf, fc1_b, nullptr, 1);
    // 9. fc2 + bias + residual
    wconv_kernel<<<dim3(512 * 2048 / 1024), dim3(256), 0, stream>>>(fc2_w, P, 512 * 2048, 512 * 2048);
    gemm_bf16<<<dim3(4, 64), dim3(256), 0, stream>>>(f1_bf, P, 2048, 512, out, nullptr, fc2_b, x_res, 0);
}

// Round 5
// 635.772 us; speedup vs baseline: 2.5205x; 1.4599x over previous
//
#include <hip/hip_runtime.h>
#include <math.h>

#define D_MODEL   512
#define D_INNER   1024
#define NHEADS    16
#define HEADDIM   64
#define D_STATE   64
#define D_CONV    7
#define D_FF      2048
#define CONV_DIM  1152
#define D_IN_PROJ 2208
#define BATCH     4
#define SEQLEN    2048
#define NTOK      (BATCH*SEQLEN)
#define EPS       1e-5f

// ---- workspace layout (float32 units) ----
// zx_bf  : bf16 8192x2208              [0, 9043968)        (f1_bf overlays after combine)
// xbc_bf : bf16 8192x1152              [9043968, 13762560)
// xT_bf  : bf16 4x1024x2048            [13762560, 17956864)
// y_fw   : f32 8192x1024               [17956864, 26345472)
// y_bw   : f32 8192x1024               [26345472, 34734080)
// sreg   : f32 4096 tiles x 4096       [34734080, 51511296)   (S-tiles during scan)
//   overlay in sreg (disjoint! hA_bf is 2,097,152 FLOATS of bf16):
//   hA_bf  = sreg[0 .. 2097152)           bf16 8192x512
//   P      = sreg[2097152 .. 2686976)     bf16 weight pad buffer (max 2304x512)
//   yg_bf  = sreg[2686976 .. 6881280)     bf16 8192x1024
//   x_res  = sreg[6881280 .. 11075584)    fp32 8192x512
#define OFF_XBCB  9043968ull
#define OFF_XT    13762560ull
#define OFF_YFW   17956864ull
#define OFF_YBW   26345472ull
#define OFF_SREG  34734080ull

typedef __bf16 bf16x8 __attribute__((ext_vector_type(8)));
typedef float  f32x4  __attribute__((ext_vector_type(4)));

__device__ __forceinline__ float siluf(float x) { return x / (1.f + expf(-x)); }
__device__ __forceinline__ float geluf(float x) { return 0.5f * x * (1.f + erff(x * 0.70710678118654752f)); }
__device__ __forceinline__ float softplusf(float x) { return fmaxf(x, 0.f) + log1pf(expf(-fabsf(x))); }
__device__ __forceinline__ int tglob(int d, int c, int t) { int s = c * 64 + t; return d ? (SEQLEN - 1 - s) : s; }
__device__ __forceinline__ unsigned short f2bf(float f) {
    unsigned int u = __float_as_uint(f);
    u += 0x7FFFu + ((u >> 16) & 1u);
    return (unsigned short)(u >> 16);
}
__device__ __forceinline__ float bf2f(unsigned short u) { return __uint_as_float((unsigned)u << 16); }
__device__ __forceinline__ void glds16(const void* g, void* l) {
    __builtin_amdgcn_global_load_lds((const __attribute__((address_space(1))) void*)g,
                                     (__attribute__((address_space(3))) void*)l, 16, 0, 0);
}

// ---------------- LayerNorm -> bf16 ----------------
__global__ __launch_bounds__(256) void ln_kernel(const float* __restrict__ x,
                                                 const float* __restrict__ w,
                                                 const float* __restrict__ b,
                                                 unsigned short* __restrict__ out, int nrows)
{
    int wid = threadIdx.x >> 6;
    int lane = threadIdx.x & 63;
    int row = blockIdx.x * 4 + wid;
    if (row >= nrows) return;
    const float* xr = x + (size_t)row * D_MODEL;
    float4 v0 = *(const float4*)(xr + lane * 8);
    float4 v1 = *(const float4*)(xr + lane * 8 + 4);
    float v[8] = {v0.x, v0.y, v0.z, v0.w, v1.x, v1.y, v1.z, v1.w};
    float s = 0.f;
#pragma unroll
    for (int i = 0; i < 8; i++) s += v[i];
#pragma unroll
    for (int m = 1; m < 64; m <<= 1) s += __shfl_xor(s, m, 64);
    float mu = s * (1.f / D_MODEL);
    float q = 0.f;
#pragma unroll
    for (int i = 0; i < 8; i++) { float dd = v[i] - mu; q += dd * dd; }
#pragma unroll
    for (int m = 1; m < 64; m <<= 1) q += __shfl_xor(q, m, 64);
    float inv = rsqrtf(q * (1.f / D_MODEL) + EPS);
    float4 w0 = *(const float4*)(w + lane * 8);
    float4 w1 = *(const float4*)(w + lane * 8 + 4);
    float4 b0 = *(const float4*)(b + lane * 8);
    float4 b1 = *(const float4*)(b + lane * 8 + 4);
    float o[8];
    o[0] = (v[0]-mu)*inv*w0.x + b0.x; o[1] = (v[1]-mu)*inv*w0.y + b0.y;
    o[2] = (v[2]-mu)*inv*w0.z + b0.z; o[3] = (v[3]-mu)*inv*w0.w + b0.w;
    o[4] = (v[4]-mu)*inv*w1.x + b1.x; o[5] = (v[5]-mu)*inv*w1.y + b1.y;
    o[6] = (v[6]-mu)*inv*w1.z + b1.z; o[7] = (v[7]-mu)*inv*w1.w + b1.w;
    unsigned short* orow = out + (size_t)row * D_MODEL + lane * 8;
    ushort4 p0, p1;
    p0.x = f2bf(o[0]); p0.y = f2bf(o[1]); p0.z = f2bf(o[2]); p0.w = f2bf(o[3]);
    p1.x = f2bf(o[4]); p1.y = f2bf(o[5]); p1.z = f2bf(o[6]); p1.w = f2bf(o[7]);
    *(ushort4*)orow = p0;
    *(ushort4*)(orow + 4) = p1;
}

// ---------------- weight fp32 -> bf16 (zero-pad to dst_n) ----------------
__global__ __launch_bounds__(256) void wconv_kernel(const float* __restrict__ src,
                                                    unsigned short* __restrict__ dst,
                                                    int src_n, int dst_n)
{
    int i = (blockIdx.x * 256 + threadIdx.x) * 4;
    if (i >= dst_n) return;
    ushort4 o;
    if (i < src_n) {
        float4 v = *(const float4*)(src + i);
        o.x = f2bf(v.x); o.y = f2bf(v.y); o.z = f2bf(v.z); o.w = f2bf(v.w);
    } else {
        o.x = o.y = o.z = o.w = 0;
    }
    *(ushort4*)(dst + i) = o;
}

// ---------------- bf16 MFMA GEMM (m97 structure) ----------------
__global__ __launch_bounds__(256, 2) void gemm_bf16(const unsigned short* __restrict__ A,
                                                    const unsigned short* __restrict__ W,
                                                    int K, int Nreal,
                                                    float* __restrict__ Cf,
                                                    unsigned short* __restrict__ Cb,
                                                    const float* __restrict__ bias,
                                                    const float* __restrict__ res, int act,
                                                    float* __restrict__ dtf)
{
    __shared__ unsigned short As[128 * 32];
    __shared__ unsigned short Ws[128 * 32];
    const int tid = threadIdx.x;
    const int wave = tid >> 6;
    const int lane = tid & 63;
    const int m0 = blockIdx.y * 128;
    const int n0 = blockIdx.x * 128;
    const int wm = (wave & 1) * 64;
    const int wn = (wave >> 1) * 64;

    const size_t gA = (size_t)(m0 + 32 * wave + (lane >> 2)) * K + (lane & 3) * 8;
    const size_t gW = (size_t)(n0 + 32 * wave + (lane >> 2)) * K + (lane & 3) * 8;
    unsigned short* lA = As + wave * 1024 + lane * 8;
    unsigned short* lW = Ws + wave * 1024 + lane * 8;

    const int fr = lane & 15;
    const int fq = (lane >> 4) * 8;
    f32x4 acc[4][4] = {};

    for (int k0 = 0; k0 < K; k0 += 32) {
        glds16(A + gA + k0, lA);
        glds16(A + gA + (size_t)16 * K + k0, lA + 512);
        glds16(W + gW + k0, lW);
        glds16(W + gW + (size_t)16 * K + k0, lW + 512);
        __syncthreads();
        bf16x8 af[4], bf[4];
#pragma unroll
        for (int mi = 0; mi < 4; mi++)
            af[mi] = *(const bf16x8*)(As + (wm + mi * 16 + fr) * 32 + fq);
#pragma unroll
        for (int ni = 0; ni < 4; ni++)
            bf[ni] = *(const bf16x8*)(Ws + (wn + ni * 16 + fr) * 32 + fq);
#pragma unroll
        for (int mi = 0; mi < 4; mi++)
#pragma unroll
            for (int ni = 0; ni < 4; ni++)
                acc[mi][ni] = __builtin_amdgcn_mfma_f32_16x16x32_bf16(af[mi], bf[ni], acc[mi][ni], 0, 0, 0);
        __syncthreads();
    }

    const int colb = n0 + wn + (lane & 15);
    const int rowb = m0 + wm + (lane >> 4) * 4;
#pragma unroll
    for (int mi = 0; mi < 4; mi++) {
#pragma unroll
        for (int ni = 0; ni < 4; ni++) {
            int col = colb + ni * 16;
            if (col < Nreal) {
#pragma unroll
                for (int r = 0; r < 4; r++) {
                    int row = rowb + mi * 16 + r;
                    float v = acc[mi][ni][r];
                    size_t idx = (size_t)row * Nreal + col;
                    if (bias) v += bias[col];
                    if (res) v += res[idx];
                    if (act) v = geluf(v);
                    if (Cb) {
                        Cb[idx] = f2bf(v);
                        if (dtf && col >= 2176) dtf[(size_t)row * 32 + (col - 2176)] = v;
                    } else Cf[idx] = v;
                }
            }
        }
    }
}

// ---------------- depthwise causal conv (k=7) + bias + SiLU, bf16 in/out ----------------
__global__ __launch_bounds__(256) void conv_kernel(const unsigned short* __restrict__ zx,
                                                   const float* __restrict__ conv_w,
                                                   const float* __restrict__ conv_b,
                                                   unsigned short* __restrict__ out)
{
    int gid = blockIdx.x * 256 + threadIdx.x;
    if (gid >= NTOK * CONV_DIM) return;
    int c = gid % CONV_DIM;
    int bt = gid / CONV_DIM;
    int t = bt & (SEQLEN - 1);
    float acc = conv_b[c];
    const unsigned short* base = zx + (size_t)bt * D_IN_PROJ + D_INNER + c;
#pragma unroll
    for (int j = 0; j < D_CONV; j++) {
        int tt = t - 6 + j;
        if (tt >= 0) acc = fmaf(conv_w[c * D_CONV + j], bf2f(base[(ptrdiff_t)(j - 6) * D_IN_PROJ]), acc);
    }
    out[(size_t)bt * CONV_DIM + c] = f2bf(siluf(acc));
}

// ---------------- transpose xs: xbc_bf[:, :1024] -> xT[b][p][t] ----------------
__global__ __launch_bounds__(256) void xpose_kernel(const unsigned short* __restrict__ xbc,
                                                    unsigned short* __restrict__ xT)
{
    int tt = blockIdx.x, pt = blockIdx.y, b = blockIdx.z;
    __shared__ unsigned short T[64][68];
    {
        int r = threadIdx.x >> 4, q = threadIdx.x & 15;
#pragma unroll
        for (int i = 0; i < 4; i++) {
            int t = tt * 64 + r + i * 16;
            ushort4 v = *(const ushort4*)(xbc + (size_t)(b * SEQLEN + t) * CONV_DIM + pt * 64 + q * 4);
            *(ushort4*)&T[r + i * 16][q * 4] = v;
        }
    }
    __syncthreads();
    {
        int p = threadIdx.x >> 4, tq = threadIdx.x & 15;
#pragma unroll
        for (int i = 0; i < 4; i++) {
            int pp = p + i * 16;
            ushort4 o;
            o.x = T[tq * 4 + 0][pp]; o.y = T[tq * 4 + 1][pp];
            o.z = T[tq * 4 + 2][pp]; o.w = T[tq * 4 + 3][pp];
            *(ushort4*)(xT + ((size_t)b * 1024 + pt * 64 + pp) * 2048 + tt * 64 + tq * 4) = o;
        }
    }
}

// ---------------- dt/cum tables (fp32 dt sidecar) ----------------
__global__ __launch_bounds__(256) void dt_table_kernel(const float* __restrict__ dtf,
                                                       const float* __restrict__ dt_bias,
                                                       const float* __restrict__ A_log,
                                                       float* __restrict__ cum_tab,
                                                       float* __restrict__ dtv_tab)
{
    int wid = blockIdx.x * 4 + (threadIdx.x >> 6);
    int lane = threadIdx.x & 63;
    int c = wid & 31, h = (wid >> 5) & 15, b = (wid >> 9) & 3, d = wid >> 11;
    int tg = tglob(d, c, lane);
    float raw = dtf[(size_t)(b * SEQLEN + tg) * 32 + d * 16 + h] + dt_bias[h];
    float dtv = softplusf(raw);
    float cum = -expf(A_log[h]) * dtv;
#pragma unroll
    for (int off = 1; off < 64; off <<= 1) {
        int src = lane - off;
        float o = __shfl(cum, src < 0 ? 0 : src, 64);
        if (lane >= off) cum += o;
    }
    cum_tab[(size_t)wid * 64 + lane] = cum;
    dtv_tab[(size_t)wid * 64 + lane] = dtv;
}

// ---------------- zero boundary rows ----------------
__global__ __launch_bounds__(256) void bzero_kernel(float* __restrict__ y_fw, float* __restrict__ y_bw)
{
    int b = blockIdx.x >> 1, d = blockIdx.x & 1;
    float* row = d ? (y_bw + (size_t)(b * SEQLEN + SEQLEN - 1) * D_INNER)
                   : (y_fw + (size_t)(b * SEQLEN) * D_INNER);
    *(float4*)(row + threadIdx.x * 4) = make_float4(0.f, 0.f, 0.f, 0.f);
}

// ---------------- K1: intra-chunk, MFMA. block=(d,b,c,hq), 4 heads/block ----------------
__global__ __launch_bounds__(256) void ssd_intra_mfma(const unsigned short* __restrict__ xbc,
                                                      const unsigned short* __restrict__ xT,
                                                      const float* __restrict__ cum_tab,
                                                      const float* __restrict__ dtv_tab,
                                                      float* __restrict__ y_fw,
                                                      float* __restrict__ y_bw)
{
    const int bid = blockIdx.x;
    const int hq = bid & 3, c = (bid >> 2) & 31, b = (bid >> 7) & 3, d = bid >> 9;
    const int tid = threadIdx.x, wave = tid >> 6, lane = tid & 63;

    __shared__ unsigned short BnMt[64 * 80];   // B[s][n] for G; then M_T[t][s]
    __shared__ unsigned short CnXt[64 * 80];   // C[t][n] for G; then X_T[p][s]
    __shared__ float Gm[64 * 68];
    __shared__ float cum_l[64], dtv_l[64];

    {
        int s = tid >> 2, nq = (tid & 3) * 16;
        int tg = tglob(d, c, s);
        const unsigned short* row = xbc + (size_t)(b * SEQLEN + tg) * CONV_DIM;
#pragma unroll
        for (int k = 0; k < 16; k += 4) {
            *(ushort4*)&BnMt[s * 80 + nq + k] = *(const ushort4*)(row + 1024 + nq + k);
            *(ushort4*)&CnXt[s * 80 + nq + k] = *(const ushort4*)(row + 1088 + nq + k);
        }
    }
    __syncthreads();
    // G[s][t] = sum_n B[s][n]*C[t][n]; wave = s-tile, 4 t-tiles
    {
        f32x4 ga[4] = {};
        const int mrow = wave * 16 + (lane & 15);
        const int kq = (lane >> 4) * 8;
#pragma unroll
        for (int k0 = 0; k0 < 64; k0 += 32) {
            bf16x8 afr = *(const bf16x8*)&BnMt[mrow * 80 + k0 + kq];
#pragma unroll
            for (int ni = 0; ni < 4; ni++) {
                bf16x8 bfr = *(const bf16x8*)&CnXt[(ni * 16 + (lane & 15)) * 80 + k0 + kq];
                ga[ni] = __builtin_amdgcn_mfma_f32_16x16x32_bf16(afr, bfr, ga[ni], 0, 0, 0);
            }
        }
        int col = lane & 15, quad = lane >> 4;
#pragma unroll
        for (int ni = 0; ni < 4; ni++)
#pragma unroll
            for (int r = 0; r < 4; r++)
                Gm[(wave * 16 + quad * 4 + r) * 68 + ni * 16 + col] = ga[ni][r];
    }

    for (int hh = 0; hh < 4; hh++) {
        const int h = hq * 4 + hh;
        __syncthreads();   // G ready (h=0) / prior head's MFMA reads done
        if (tid < 64) {
            int flat = ((d * 4 + b) * 16 + h) * 32 + c;
            cum_l[tid] = cum_tab[(size_t)flat * 64 + tid];
            dtv_l[tid] = dtv_tab[(size_t)flat * 64 + tid];
        }
        // stage X_T[p][s] from xT (coalesced along t)
        {
            const unsigned short* xrow = xT + ((size_t)b * 1024 + h * 64) * 2048;
            int p = tid >> 4, tq = tid & 15;
#pragma unroll
            for (int pi = 0; pi < 4; pi++, p += 16) {
                if (d == 0) {
                    ushort4 v = *(const ushort4*)(xrow + (size_t)p * 2048 + c * 64 + tq * 4);
                    *(ushort4*)&CnXt[p * 80 + tq * 4] = v;
                } else {
                    int base = SEQLEN - 64 - c * 64;
                    ushort4 v = *(const ushort4*)(xrow + (size_t)p * 2048 + base + (15 - tq) * 4);
                    CnXt[p * 80 + tq * 4 + 0] = v.w;
                    CnXt[p * 80 + tq * 4 + 1] = v.z;
                    CnXt[p * 80 + tq * 4 + 2] = v.y;
                    CnXt[p * 80 + tq * 4 + 3] = v.x;
                }
            }
        }
        __syncthreads();
        // M_T[t][s] = (s<=t) ? G[s][t]*exp(cum_t-cum_s)*dtv_s : 0
        {
            int s = tid & 63, tq = tid >> 6;
            float cs = cum_l[s], dv = dtv_l[s];
#pragma unroll
            for (int j = 0; j < 16; j++) {
                int t = tq * 16 + j;
                float g = Gm[s * 68 + t];
                float m = (s <= t) ? g * expf(cum_l[t] - cs) * dv : 0.f;
                BnMt[t * 80 + s] = f2bf(m);
            }
        }
        __syncthreads();
        // Y[t][p] = sum_s M_T[t][s] * X_T[p][s]; wave = t-tile, 4 p-tiles
        {
            f32x4 acc[4] = {};
            const int mrow = wave * 16 + (lane & 15);
            const int kq = (lane >> 4) * 8;
#pragma unroll
            for (int k0 = 0; k0 < 64; k0 += 32) {
                bf16x8 afr = *(const bf16x8*)&BnMt[mrow * 80 + k0 + kq];
#pragma unroll
                for (int ni = 0; ni < 4; ni++) {
                    bf16x8 bfr = *(const bf16x8*)&CnXt[(ni * 16 + (lane & 15)) * 80 + k0 + kq];
                    acc[ni] = __builtin_amdgcn_mfma_f32_16x16x32_bf16(afr, bfr, acc[ni], 0, 0, 0);
                }
            }
            float* ybuf = d ? y_bw : y_fw;
            int quad = lane >> 4, col0 = lane & 15;
#pragma unroll
            for (int r = 0; r < 4; r++) {
                int tl = wave * 16 + quad * 4 + r;
                int tg = tglob(d, c, tl);
                int tout = d ? (tg - 1) : (tg + 1);
                if (tout >= 0 && tout < SEQLEN) {
                    float* yp = ybuf + (size_t)(b * SEQLEN + tout) * D_INNER + h * 64;
#pragma unroll
                    for (int ni = 0; ni < 4; ni++)
                        yp[ni * 16 + col0] = acc[ni][r];
                }
            }
        }
    }
}

// ---------------- K2: per-chunk state S'[p][n] (VALU, bf16 reads) ----------------
__global__ __launch_bounds__(256) void ssd_state_kernel(const unsigned short* __restrict__ xbc,
                                                        const float* __restrict__ cum_tab,
                                                        const float* __restrict__ dtv_tab,
                                                        float* __restrict__ sreg)
{
    const int flat = blockIdx.x;
    const int c = flat & 31, h = (flat >> 5) & 15, b = (flat >> 9) & 3, d = flat >> 11;
    const int tid = threadIdx.x;
    const int ty = tid >> 4, tx = tid & 15;

    __shared__ float Bm[64][64];
    __shared__ float Xw[64][64];
    __shared__ float cum_l[64], dtv_l[64];

    if (tid < 64) {
        cum_l[tid] = cum_tab[(size_t)flat * 64 + tid];
        dtv_l[tid] = dtv_tab[(size_t)flat * 64 + tid];
    }
    __syncthreads();
    float clast = cum_l[63];
    for (int idx = tid; idx < 1024; idx += 256) {
        int s = idx >> 4, q = idx & 15;
        int tg = tglob(d, c, s);
        const unsigned short* row = xbc + (size_t)(b * SEQLEN + tg) * CONV_DIM;
        ushort4 ub = *(const ushort4*)(row + 1024 + q * 4);
        ushort4 ux = *(const ushort4*)(row + h * 64 + q * 4);
        float w = expf(clast - cum_l[s]) * dtv_l[s];
        Bm[s][q*4+0] = bf2f(ub.x); Bm[s][q*4+1] = bf2f(ub.y);
        Bm[s][q*4+2] = bf2f(ub.z); Bm[s][q*4+3] = bf2f(ub.w);
        Xw[s][q*4+0] = bf2f(ux.x)*w; Xw[s][q*4+1] = bf2f(ux.y)*w;
        Xw[s][q*4+2] = bf2f(ux.z)*w; Xw[s][q*4+3] = bf2f(ux.w)*w;
    }
    __syncthreads();
    // S'[p][n] = sum_s Xw[s][p] * Bm[s][n]
    float acc[4][4] = {};
    for (int s = 0; s < 64; s++) {
        float4 xv = *(const float4*)&Xw[s][ty * 4];
        float4 bv = *(const float4*)&Bm[s][tx * 4];
        float xx[4] = {xv.x, xv.y, xv.z, xv.w};
        float bb[4] = {bv.x, bv.y, bv.z, bv.w};
#pragma unroll
        for (int i = 0; i < 4; i++)
#pragma unroll
            for (int j = 0; j < 4; j++) acc[i][j] = fmaf(xx[i], bb[j], acc[i][j]);
    }
    float* st = sreg + (size_t)flat * 4096;
#pragma unroll
    for (int i = 0; i < 4; i++)
        *(float4*)&st[(size_t)(ty * 4 + i) * 64 + tx * 4] =
            make_float4(acc[i][0], acc[i][1], acc[i][2], acc[i][3]);
}

// ---------------- K3: serial chunk scan (elementwise on S'[p][n] tiles) ----------------
__global__ __launch_bounds__(256) void ssd_chunkscan_kernel(const float* __restrict__ cum_tab,
                                                            float* __restrict__ sreg)
{
    const int g = blockIdx.x;
    const int tid = threadIdx.x;
    const int base = g * 32;
    float4 hr[4] = {make_float4(0,0,0,0), make_float4(0,0,0,0), make_float4(0,0,0,0), make_float4(0,0,0,0)};
    for (int c = 0; c < 32; c++) {
        int flat = base + c;
        float dec = expf(cum_tab[(size_t)flat * 64 + 63]);
        float* Sp = sreg + (size_t)flat * 4096 + tid * 16;
        float4 s0 = *(float4*)(Sp + 0);
        float4 s1 = *(float4*)(Sp + 4);
        float4 s2 = *(float4*)(Sp + 8);
        float4 s3 = *(float4*)(Sp + 12);
        *(float4*)(Sp + 0) = hr[0];
        *(float4*)(Sp + 4) = hr[1];
        *(float4*)(Sp + 8) = hr[2];
        *(float4*)(Sp + 12) = hr[3];
        hr[0].x = hr[0].x * dec + s0.x; hr[0].y = hr[0].y * dec + s0.y; hr[0].z = hr[0].z * dec + s0.z; hr[0].w = hr[0].w * dec + s0.w;
        hr[1].x = hr[1].x * dec + s1.x; hr[1].y = hr[1].y * dec + s1.y; hr[1].z = hr[1].z * dec + s1.z; hr[1].w = hr[1].w * dec + s1.w;
        hr[2].x = hr[2].x * dec + s2.x; hr[2].y = hr[2].y * dec + s2.y; hr[2].z = hr[2].z * dec + s2.z; hr[2].w = hr[2].w * dec + s2.w;
        hr[3].x = hr[3].x * dec + s3.x; hr[3].y = hr[3].y * dec + s3.y; hr[3].z = hr[3].z * dec + s3.z; hr[3].w = hr[3].w * dec + s3.w;
    }
}

// ---------------- K4: inter-chunk Y += a_t * C_t . h (plain add, unique owner) ----------------
__global__ __launch_bounds__(256) void ssd_inter_kernel(const unsigned short* __restrict__ xbc,
                                                        const float* __restrict__ cum_tab,
                                                        const float* __restrict__ sreg,
                                                        float* __restrict__ y_fw,
                                                        float* __restrict__ y_bw)
{
    const int flat = blockIdx.x;
    const int c = flat & 31;
    if (c == 0) return;
    const int h = (flat >> 5) & 15, b = (flat >> 9) & 3, d = flat >> 11;
    const int tid = threadIdx.x;
    const int ty = tid >> 4, tx = tid & 15;

    __shared__ float C_T[64][68];
    __shared__ float h_T[64][64];   // [p][n]
    __shared__ float cum_l[64];

    if (tid < 64) cum_l[tid] = cum_tab[(size_t)flat * 64 + tid];
    {
        const float* st = sreg + (size_t)flat * 4096;
        for (int idx = tid; idx < 1024; idx += 256) {
            int p = idx >> 4, q = idx & 15;
            *(float4*)&h_T[p][q * 4] = *(const float4*)(st + (size_t)p * 64 + q * 4);
        }
    }
    for (int idx = tid; idx < 1024; idx += 256) {
        int s = idx >> 4, q = idx & 15;
        int tg = tglob(d, c, s);
        ushort4 uc = *(const ushort4*)(xbc + (size_t)(b * SEQLEN + tg) * CONV_DIM + 1088 + q * 4);
        C_T[q*4+0][s] = bf2f(uc.x); C_T[q*4+1][s] = bf2f(uc.y);
        C_T[q*4+2][s] = bf2f(uc.z); C_T[q*4+3][s] = bf2f(uc.w);
    }
    __syncthreads();
    // Y[t][p] = sum_n C[t][n] h_T[p][n]
    float acc[4][4] = {};
    for (int n = 0; n < 64; n++) {
        float4 cv = *(const float4*)&C_T[n][ty * 4];
        float hh0 = h_T[tx*4+0][n], hh1 = h_T[tx*4+1][n], hh2 = h_T[tx*4+2][n], hh3 = h_T[tx*4+3][n];
        float cc[4] = {cv.x, cv.y, cv.z, cv.w};
        float hh[4] = {hh0, hh1, hh2, hh3};
#pragma unroll
        for (int i = 0; i < 4; i++)
#pragma unroll
            for (int j = 0; j < 4; j++) acc[i][j] = fmaf(cc[i], hh[j], acc[i][j]);
    }
    float* ybuf = d ? y_bw : y_fw;
#pragma unroll
    for (int i = 0; i < 4; i++) {
        int tl = ty * 4 + i;
        float a = expf(cum_l[tl]);
        int tg = tglob(d, c, tl);
        int tout = d ? (tg - 1) : (tg + 1);
        if (tout >= 0 && tout < SEQLEN) {
            float* yp = ybuf + (size_t)(b * SEQLEN + tout) * D_INNER + h * 64 + tx * 4;
#pragma unroll
            for (int j = 0; j < 4; j++) yp[j] += acc[i][j] * a;
        }
    }
}

// ---------------- combine -> bf16 yg ----------------
__global__ __launch_bounds__(256) void combine_kernel(const unsigned short* __restrict__ zx,
                                                      const unsigned short* __restrict__ xbc,
                                                      const float* __restrict__ y_fw,
                                                      const float* __restrict__ y_bw,
                                                      const float* __restrict__ Dp,
                                                      const float* __restrict__ rms_w,
                                                      unsigned short* __restrict__ yg)
{
    int row = blockIdx.x;
    int i = threadIdx.x * 4;
    float4 yf = *(const float4*)(y_fw + (size_t)row * D_INNER + i);
    float4 yb = *(const float4*)(y_bw + (size_t)row * D_INNER + i);
    ushort4 uxs = *(const ushort4*)(xbc + (size_t)row * CONV_DIM + i);
    ushort4 uz  = *(const ushort4*)(zx + (size_t)row * D_IN_PROJ + i);
    float dp = Dp[i >> 6];
    float g[4];
    g[0] = (yf.x + yb.x + bf2f(uxs.x) * dp) * siluf(bf2f(uz.x));
    g[1] = (yf.y + yb.y + bf2f(uxs.y) * dp) * siluf(bf2f(uz.y));
    g[2] = (yf.z + yb.z + bf2f(uxs.z) * dp) * siluf(bf2f(uz.z));
    g[3] = (yf.w + yb.w + bf2f(uxs.w) * dp) * siluf(bf2f(uz.w));
    float ss = g[0]*g[0] + g[1]*g[1] + g[2]*g[2] + g[3]*g[3];
#pragma unroll
    for (int m = 1; m < 64; m <<= 1) ss += __shfl_xor(ss, m, 64);
    __shared__ float red[4];
    if ((threadIdx.x & 63) == 0) red[threadIdx.x >> 6] = ss;
    __syncthreads();
    ss = red[0] + red[1] + red[2] + red[3];
    float scale = rsqrtf(ss * (1.f / D_INNER) + EPS);
    float4 rw = *(const float4*)(rms_w + i);
    ushort4 o;
    o.x = f2bf(g[0] * scale * rw.x); o.y = f2bf(g[1] * scale * rw.y);
    o.z = f2bf(g[2] * scale * rw.z); o.w = f2bf(g[3] * scale * rw.w);
    *(ushort4*)(yg + (size_t)row * D_INNER + i) = o;
}

// ---------------- launch ----------------
extern "C" void kernel_launch(void* const* d_in, const int* in_sizes, int n_in,
                              void* d_out, int out_size, void* d_ws, size_t ws_size,
                              hipStream_t stream)
{
    const float* x         = (const float*)d_in[0];
    const float* ln1_w     = (const float*)d_in[1];
    const float* ln1_b     = (const float*)d_in[2];
    const float* in_proj_w = (const float*)d_in[3];
    const float* conv_w    = (const float*)d_in[4];
    const float* conv_b    = (const float*)d_in[5];
    const float* dt_bias   = (const float*)d_in[6];
    const float* A_log     = (const float*)d_in[7];
    const float* Dp        = (const float*)d_in[8];
    const float* rms_w     = (const float*)d_in[9];
    const float* out_proj_w= (const float*)d_in[10];
    const float* ln2_w     = (const float*)d_in[11];
    const float* ln2_b     = (const float*)d_in[12];
    const float* fc1_w     = (const float*)d_in[13];
    const float* fc1_b     = (const float*)d_in[14];
    const float* fc2_w     = (const float*)d_in[15];
    const float* fc2_b     = (const float*)d_in[16];
    float* out = (float*)d_out;

    float* ws0 = (float*)d_ws;
    unsigned short* zx_bf  = (unsigned short*)ws0;
    unsigned short* xbc_bf = (unsigned short*)(ws0 + OFF_XBCB);
    unsigned short* xT_bf  = (unsigned short*)(ws0 + OFF_XT);
    float* y_fw = ws0 + OFF_YFW;
    float* y_bw = ws0 + OFF_YBW;
    float* sreg = ws0 + OFF_SREG;
    unsigned short* hA_bf = (unsigned short*)sreg;               // [0, 2097152) floats
    unsigned short* P     = (unsigned short*)(sreg + 2097152);   // [2097152, 2686976)
    unsigned short* yg_bf = (unsigned short*)(sreg + 2686976);   // [2686976, 6881280)
    float* x_res          = sreg + 6881280;                      // [6881280, 11075584)
    unsigned short* f1_bf = (unsigned short*)ws0;    // overlays zx_bf (dead after combine)
    float* cum_tab = out;                            // d_out scratch, overwritten by fc2
    float* dtv_tab = out + 262144;
    float* dtf     = out + 524288;                   // fp32 dt sidecar 8192x32

    // 1. LN1 -> bf16
    ln_kernel<<<dim3(NTOK / 4), dim3(256), 0, stream>>>(x, ln1_w, ln1_b, hA_bf, NTOK);
    // 2. in_proj -> bf16 zx (+ fp32 dt sidecar)
    wconv_kernel<<<dim3(2304 * 512 / 1024), dim3(256), 0, stream>>>(in_proj_w, P, 2208 * 512, 2304 * 512);
    gemm_bf16<<<dim3(18, 64), dim3(256), 0, stream>>>(hA_bf, P, 512, 2208, nullptr, zx_bf, nullptr, nullptr, 0, dtf);
    // 3. conv (bf16 in/out)
    conv_kernel<<<dim3(NTOK * CONV_DIM / 256), dim3(256), 0, stream>>>(zx_bf, conv_w, conv_b, xbc_bf);
    // 4. transpose xs -> xT
    xpose_kernel<<<dim3(32, 16, 4), dim3(256), 0, stream>>>(xbc_bf, xT_bf);
    // 5. tables + boundary zero
    dt_table_kernel<<<dim3(1024), dim3(256), 0, stream>>>(dtf, dt_bias, A_log, cum_tab, dtv_tab);
    bzero_kernel<<<dim3(8), dim3(256), 0, stream>>>(y_fw, y_bw);
    // 6. SSD
    ssd_intra_mfma<<<dim3(1024), dim3(256), 0, stream>>>(xbc_bf, xT_bf, cum_tab, dtv_tab, y_fw, y_bw);
    ssd_state_kernel<<<dim3(4096), dim3(256), 0, stream>>>(xbc_bf, cum_tab, dtv_tab, sreg);
    ssd_chunkscan_kernel<<<dim3(128), dim3(256), 0, stream>>>(cum_tab, sreg);
    ssd_inter_kernel<<<dim3(4096), dim3(256), 0, stream>>>(xbc_bf, cum_tab, sreg, y_fw, y_bw);
    // 7. combine -> bf16 yg
    combine_kernel<<<dim3(NTOK), dim3(256), 0, stream>>>(zx_bf, xbc_bf, y_fw, y_bw, Dp, rms_w, yg_bf);
    // 8. out_proj + residual(x)
    wconv_kernel<<<dim3(512 * 1024 / 1024), dim3(256), 0, stream>>>(out_proj_w, P, 512 * 1024, 512 * 1024);
    gemm_bf16<<<dim3(4, 64), dim3(256), 0, stream>>>(yg_bf, P, 1024, 512, x_res, nullptr, nullptr, x, 0, nullptr);
    // 9. LN2 -> bf16
    ln_kernel<<<dim3(NTOK / 4), dim3(256), 0, stream>>>(x_res, ln2_w, ln2_b, hA_bf, NTOK);
    // 10. fc1 + bias + GELU -> bf16
    wconv_kernel<<<dim3(2048 * 512 / 1024), dim3(256), 0, stream>>>(fc1_w, P, 2048 * 512, 2048 * 512);
    gemm_bf16<<<dim3(16, 64), dim3(256), 0, stream>>>(hA_bf, P, 512, 2048, nullptr, f1_bf, fc1_b, nullptr, 1, nullptr);
    // 11. fc2 + bias + residual
    wconv_kernel<<<dim3(512 * 2048 / 1024), dim3(256), 0, stream>>>(fc2_w, P, 512 * 2048, 512 * 2048);
    gemm_bf16<<<dim3(4, 64), dim3(256), 0, stream>>>(f1_bf, P, 2048, 512, out, nullptr, fc2_b, x_res, 0, nullptr);
}

// Round 6
// 514.435 us; speedup vs baseline: 3.1151x; 1.2359x over previous
//
#include <hip/hip_runtime.h>
#include <math.h>

#define D_MODEL   512
#define D_INNER   1024
#define NHEADS    16
#define HEADDIM   64
#define D_STATE   64
#define D_CONV    7
#define D_FF      2048
#define CONV_DIM  1152
#define D_IN_PROJ 2208
#define BATCH     4
#define SEQLEN    2048
#define NTOK      (BATCH*SEQLEN)
#define EPS       1e-5f

// ---- workspace layout (float32 units) ----
// zx_bf  : bf16 8192x2208              [0, 9043968)        (f1_bf overlays after combine)
// xbc_bf : bf16 8192x1152              [9043968, 13762560)
// xT_bf  : bf16 4x1024x2048            [13762560, 17956864)
// y_fw   : f32 8192x1024               [17956864, 26345472)
// y_bw   : f32 8192x1024               [26345472, 34734080)
// sreg   : [34734080, 51511296)  16.77M floats
//   during scan: S-tiles bf16 4096 x 4096 shorts = [0 .. 8388608) floats of sreg
//   overlay (lifetimes disjoint from S-tiles):
//   hA_bf  = sreg[0 .. 2097152)           bf16 8192x512   (written st.1/9, read st.2/10)
//   P      = sreg[2097152 .. 2686976)     bf16 weight pad (written st.2 then st.8+, after S dead)
//   yg_bf  = sreg[2686976 .. 6881280)     bf16 8192x1024  (written st.7, after inter)
//   x_res  = sreg[6881280 .. 11075584)    fp32 8192x512   (written st.8)
#define OFF_XBCB  9043968ull
#define OFF_XT    13762560ull
#define OFF_YFW   17956864ull
#define OFF_YBW   26345472ull
#define OFF_SREG  34734080ull

typedef __bf16 bf16x8 __attribute__((ext_vector_type(8)));
typedef float  f32x4  __attribute__((ext_vector_type(4)));

__device__ __forceinline__ float siluf(float x) { return x / (1.f + expf(-x)); }
__device__ __forceinline__ float geluf(float x) { return 0.5f * x * (1.f + erff(x * 0.70710678118654752f)); }
__device__ __forceinline__ float softplusf(float x) { return fmaxf(x, 0.f) + log1pf(expf(-fabsf(x))); }
__device__ __forceinline__ int tglob(int d, int c, int t) { int s = c * 64 + t; return d ? (SEQLEN - 1 - s) : s; }
__device__ __forceinline__ unsigned short f2bf(float f) {
    unsigned int u = __float_as_uint(f);
    u += 0x7FFFu + ((u >> 16) & 1u);
    return (unsigned short)(u >> 16);
}
__device__ __forceinline__ float bf2f(unsigned short u) { return __uint_as_float((unsigned)u << 16); }
__device__ __forceinline__ void glds16(const void* g, void* l) {
    __builtin_amdgcn_global_load_lds((const __attribute__((address_space(1))) void*)g,
                                     (__attribute__((address_space(3))) void*)l, 16, 0, 0);
}

// ---------------- LayerNorm -> bf16 ----------------
__global__ __launch_bounds__(256) void ln_kernel(const float* __restrict__ x,
                                                 const float* __restrict__ w,
                                                 const float* __restrict__ b,
                                                 unsigned short* __restrict__ out, int nrows)
{
    int wid = threadIdx.x >> 6;
    int lane = threadIdx.x & 63;
    int row = blockIdx.x * 4 + wid;
    if (row >= nrows) return;
    const float* xr = x + (size_t)row * D_MODEL;
    float4 v0 = *(const float4*)(xr + lane * 8);
    float4 v1 = *(const float4*)(xr + lane * 8 + 4);
    float v[8] = {v0.x, v0.y, v0.z, v0.w, v1.x, v1.y, v1.z, v1.w};
    float s = 0.f;
#pragma unroll
    for (int i = 0; i < 8; i++) s += v[i];
#pragma unroll
    for (int m = 1; m < 64; m <<= 1) s += __shfl_xor(s, m, 64);
    float mu = s * (1.f / D_MODEL);
    float q = 0.f;
#pragma unroll
    for (int i = 0; i < 8; i++) { float dd = v[i] - mu; q += dd * dd; }
#pragma unroll
    for (int m = 1; m < 64; m <<= 1) q += __shfl_xor(q, m, 64);
    float inv = rsqrtf(q * (1.f / D_MODEL) + EPS);
    float4 w0 = *(const float4*)(w + lane * 8);
    float4 w1 = *(const float4*)(w + lane * 8 + 4);
    float4 b0 = *(const float4*)(b + lane * 8);
    float4 b1 = *(const float4*)(b + lane * 8 + 4);
    float o[8];
    o[0] = (v[0]-mu)*inv*w0.x + b0.x; o[1] = (v[1]-mu)*inv*w0.y + b0.y;
    o[2] = (v[2]-mu)*inv*w0.z + b0.z; o[3] = (v[3]-mu)*inv*w0.w + b0.w;
    o[4] = (v[4]-mu)*inv*w1.x + b1.x; o[5] = (v[5]-mu)*inv*w1.y + b1.y;
    o[6] = (v[6]-mu)*inv*w1.z + b1.z; o[7] = (v[7]-mu)*inv*w1.w + b1.w;
    unsigned short* orow = out + (size_t)row * D_MODEL + lane * 8;
    ushort4 p0, p1;
    p0.x = f2bf(o[0]); p0.y = f2bf(o[1]); p0.z = f2bf(o[2]); p0.w = f2bf(o[3]);
    p1.x = f2bf(o[4]); p1.y = f2bf(o[5]); p1.z = f2bf(o[6]); p1.w = f2bf(o[7]);
    *(ushort4*)orow = p0;
    *(ushort4*)(orow + 4) = p1;
}

// ---------------- weight fp32 -> bf16 (zero-pad to dst_n) ----------------
__global__ __launch_bounds__(256) void wconv_kernel(const float* __restrict__ src,
                                                    unsigned short* __restrict__ dst,
                                                    int src_n, int dst_n)
{
    int i = (blockIdx.x * 256 + threadIdx.x) * 4;
    if (i >= dst_n) return;
    ushort4 o;
    if (i < src_n) {
        float4 v = *(const float4*)(src + i);
        o.x = f2bf(v.x); o.y = f2bf(v.y); o.z = f2bf(v.z); o.w = f2bf(v.w);
    } else {
        o.x = o.y = o.z = o.w = 0;
    }
    *(ushort4*)(dst + i) = o;
}

// ---------------- bf16 MFMA GEMM (m97 structure) ----------------
__global__ __launch_bounds__(256, 2) void gemm_bf16(const unsigned short* __restrict__ A,
                                                    const unsigned short* __restrict__ W,
                                                    int K, int Nreal,
                                                    float* __restrict__ Cf,
                                                    unsigned short* __restrict__ Cb,
                                                    const float* __restrict__ bias,
                                                    const float* __restrict__ res, int act,
                                                    float* __restrict__ dtf)
{
    __shared__ unsigned short As[128 * 32];
    __shared__ unsigned short Ws[128 * 32];
    const int tid = threadIdx.x;
    const int wave = tid >> 6;
    const int lane = tid & 63;
    const int m0 = blockIdx.y * 128;
    const int n0 = blockIdx.x * 128;
    const int wm = (wave & 1) * 64;
    const int wn = (wave >> 1) * 64;

    const size_t gA = (size_t)(m0 + 32 * wave + (lane >> 2)) * K + (lane & 3) * 8;
    const size_t gW = (size_t)(n0 + 32 * wave + (lane >> 2)) * K + (lane & 3) * 8;
    unsigned short* lA = As + wave * 1024 + lane * 8;
    unsigned short* lW = Ws + wave * 1024 + lane * 8;

    const int fr = lane & 15;
    const int fq = (lane >> 4) * 8;
    f32x4 acc[4][4] = {};

    for (int k0 = 0; k0 < K; k0 += 32) {
        glds16(A + gA + k0, lA);
        glds16(A + gA + (size_t)16 * K + k0, lA + 512);
        glds16(W + gW + k0, lW);
        glds16(W + gW + (size_t)16 * K + k0, lW + 512);
        __syncthreads();
        bf16x8 af[4], bf[4];
#pragma unroll
        for (int mi = 0; mi < 4; mi++)
            af[mi] = *(const bf16x8*)(As + (wm + mi * 16 + fr) * 32 + fq);
#pragma unroll
        for (int ni = 0; ni < 4; ni++)
            bf[ni] = *(const bf16x8*)(Ws + (wn + ni * 16 + fr) * 32 + fq);
#pragma unroll
        for (int mi = 0; mi < 4; mi++)
#pragma unroll
            for (int ni = 0; ni < 4; ni++)
                acc[mi][ni] = __builtin_amdgcn_mfma_f32_16x16x32_bf16(af[mi], bf[ni], acc[mi][ni], 0, 0, 0);
        __syncthreads();
    }

    const int colb = n0 + wn + (lane & 15);
    const int rowb = m0 + wm + (lane >> 4) * 4;
#pragma unroll
    for (int mi = 0; mi < 4; mi++) {
#pragma unroll
        for (int ni = 0; ni < 4; ni++) {
            int col = colb + ni * 16;
            if (col < Nreal) {
#pragma unroll
                for (int r = 0; r < 4; r++) {
                    int row = rowb + mi * 16 + r;
                    float v = acc[mi][ni][r];
                    size_t idx = (size_t)row * Nreal + col;
                    if (bias) v += bias[col];
                    if (res) v += res[idx];
                    if (act) v = geluf(v);
                    if (Cb) {
                        Cb[idx] = f2bf(v);
                        if (dtf && col >= 2176) dtf[(size_t)row * 32 + (col - 2176)] = v;
                    } else Cf[idx] = v;
                }
            }
        }
    }
}

// ---------------- depthwise causal conv (k=7) + bias + SiLU, bf16 in/out ----------------
__global__ __launch_bounds__(256) void conv_kernel(const unsigned short* __restrict__ zx,
                                                   const float* __restrict__ conv_w,
                                                   const float* __restrict__ conv_b,
                                                   unsigned short* __restrict__ out)
{
    int gid = blockIdx.x * 256 + threadIdx.x;
    if (gid >= NTOK * CONV_DIM) return;
    int c = gid % CONV_DIM;
    int bt = gid / CONV_DIM;
    int t = bt & (SEQLEN - 1);
    float acc = conv_b[c];
    const unsigned short* base = zx + (size_t)bt * D_IN_PROJ + D_INNER + c;
#pragma unroll
    for (int j = 0; j < D_CONV; j++) {
        int tt = t - 6 + j;
        if (tt >= 0) acc = fmaf(conv_w[c * D_CONV + j], bf2f(base[(ptrdiff_t)(j - 6) * D_IN_PROJ]), acc);
    }
    out[(size_t)bt * CONV_DIM + c] = f2bf(siluf(acc));
}

// ---------------- transpose xs: xbc_bf[:, :1024] -> xT[b][p][t] ----------------
__global__ __launch_bounds__(256) void xpose_kernel(const unsigned short* __restrict__ xbc,
                                                    unsigned short* __restrict__ xT)
{
    int tt = blockIdx.x, pt = blockIdx.y, b = blockIdx.z;
    __shared__ unsigned short T[64][68];
    {
        int r = threadIdx.x >> 4, q = threadIdx.x & 15;
#pragma unroll
        for (int i = 0; i < 4; i++) {
            int t = tt * 64 + r + i * 16;
            ushort4 v = *(const ushort4*)(xbc + (size_t)(b * SEQLEN + t) * CONV_DIM + pt * 64 + q * 4);
            *(ushort4*)&T[r + i * 16][q * 4] = v;
        }
    }
    __syncthreads();
    {
        int p = threadIdx.x >> 4, tq = threadIdx.x & 15;
#pragma unroll
        for (int i = 0; i < 4; i++) {
            int pp = p + i * 16;
            ushort4 o;
            o.x = T[tq * 4 + 0][pp]; o.y = T[tq * 4 + 1][pp];
            o.z = T[tq * 4 + 2][pp]; o.w = T[tq * 4 + 3][pp];
            *(ushort4*)(xT + ((size_t)b * 1024 + pt * 64 + pp) * 2048 + tt * 64 + tq * 4) = o;
        }
    }
}

// ---------------- dt/cum tables (fp32 dt sidecar) ----------------
__global__ __launch_bounds__(256) void dt_table_kernel(const float* __restrict__ dtf,
                                                       const float* __restrict__ dt_bias,
                                                       const float* __restrict__ A_log,
                                                       float* __restrict__ cum_tab,
                                                       float* __restrict__ dtv_tab)
{
    int wid = blockIdx.x * 4 + (threadIdx.x >> 6);
    int lane = threadIdx.x & 63;
    int c = wid & 31, h = (wid >> 5) & 15, b = (wid >> 9) & 3, d = wid >> 11;
    int tg = tglob(d, c, lane);
    float raw = dtf[(size_t)(b * SEQLEN + tg) * 32 + d * 16 + h] + dt_bias[h];
    float dtv = softplusf(raw);
    float cum = -expf(A_log[h]) * dtv;
#pragma unroll
    for (int off = 1; off < 64; off <<= 1) {
        int src = lane - off;
        float o = __shfl(cum, src < 0 ? 0 : src, 64);
        if (lane >= off) cum += o;
    }
    cum_tab[(size_t)wid * 64 + lane] = cum;
    dtv_tab[(size_t)wid * 64 + lane] = dtv;
}

// ---------------- zero boundary rows ----------------
__global__ __launch_bounds__(256) void bzero_kernel(float* __restrict__ y_fw, float* __restrict__ y_bw)
{
    int b = blockIdx.x >> 1, d = blockIdx.x & 1;
    float* row = d ? (y_bw + (size_t)(b * SEQLEN + SEQLEN - 1) * D_INNER)
                   : (y_fw + (size_t)(b * SEQLEN) * D_INNER);
    *(float4*)(row + threadIdx.x * 4) = make_float4(0.f, 0.f, 0.f, 0.f);
}

// ---------------- K1: intra-chunk, MFMA. block=(d,b,c,hq), 4 heads/block ----------------
__global__ __launch_bounds__(256) void ssd_intra_mfma(const unsigned short* __restrict__ xbc,
                                                      const unsigned short* __restrict__ xT,
                                                      const float* __restrict__ cum_tab,
                                                      const float* __restrict__ dtv_tab,
                                                      float* __restrict__ y_fw,
                                                      float* __restrict__ y_bw)
{
    const int bid = blockIdx.x;
    const int hq = bid & 3, c = (bid >> 2) & 31, b = (bid >> 7) & 3, d = bid >> 9;
    const int tid = threadIdx.x, wave = tid >> 6, lane = tid & 63;

    __shared__ unsigned short BnMt[64 * 80];   // B[s][n] for G; then M_T[t][s]
    __shared__ unsigned short CnXt[64 * 80];   // C[t][n] for G; then X_T[p][s]
    __shared__ float Gm[64 * 68];
    __shared__ float cum_l[64], dtv_l[64];

    {
        int s = tid >> 2, nq = (tid & 3) * 16;
        int tg = tglob(d, c, s);
        const unsigned short* row = xbc + (size_t)(b * SEQLEN + tg) * CONV_DIM;
#pragma unroll
        for (int k = 0; k < 16; k += 4) {
            *(ushort4*)&BnMt[s * 80 + nq + k] = *(const ushort4*)(row + 1024 + nq + k);
            *(ushort4*)&CnXt[s * 80 + nq + k] = *(const ushort4*)(row + 1088 + nq + k);
        }
    }
    __syncthreads();
    // G[s][t] = sum_n B[s][n]*C[t][n]; wave = s-tile, 4 t-tiles
    {
        f32x4 ga[4] = {};
        const int mrow = wave * 16 + (lane & 15);
        const int kq = (lane >> 4) * 8;
#pragma unroll
        for (int k0 = 0; k0 < 64; k0 += 32) {
            bf16x8 afr = *(const bf16x8*)&BnMt[mrow * 80 + k0 + kq];
#pragma unroll
            for (int ni = 0; ni < 4; ni++) {
                bf16x8 bfr = *(const bf16x8*)&CnXt[(ni * 16 + (lane & 15)) * 80 + k0 + kq];
                ga[ni] = __builtin_amdgcn_mfma_f32_16x16x32_bf16(afr, bfr, ga[ni], 0, 0, 0);
            }
        }
        int col = lane & 15, quad = lane >> 4;
#pragma unroll
        for (int ni = 0; ni < 4; ni++)
#pragma unroll
            for (int r = 0; r < 4; r++)
                Gm[(wave * 16 + quad * 4 + r) * 68 + ni * 16 + col] = ga[ni][r];
    }

    for (int hh = 0; hh < 4; hh++) {
        const int h = hq * 4 + hh;
        __syncthreads();
        if (tid < 64) {
            int flat = ((d * 4 + b) * 16 + h) * 32 + c;
            cum_l[tid] = cum_tab[(size_t)flat * 64 + tid];
            dtv_l[tid] = dtv_tab[(size_t)flat * 64 + tid];
        }
        // stage X_T[p][s] from xT (coalesced along t)
        {
            const unsigned short* xrow = xT + ((size_t)b * 1024 + h * 64) * 2048;
            int p = tid >> 4, tq = tid & 15;
#pragma unroll
            for (int pi = 0; pi < 4; pi++, p += 16) {
                if (d == 0) {
                    ushort4 v = *(const ushort4*)(xrow + (size_t)p * 2048 + c * 64 + tq * 4);
                    *(ushort4*)&CnXt[p * 80 + tq * 4] = v;
                } else {
                    int base = SEQLEN - 64 - c * 64;
                    ushort4 v = *(const ushort4*)(xrow + (size_t)p * 2048 + base + (15 - tq) * 4);
                    CnXt[p * 80 + tq * 4 + 0] = v.w;
                    CnXt[p * 80 + tq * 4 + 1] = v.z;
                    CnXt[p * 80 + tq * 4 + 2] = v.y;
                    CnXt[p * 80 + tq * 4 + 3] = v.x;
                }
            }
        }
        __syncthreads();
        // M_T[t][s] = (s<=t) ? G[s][t]*exp(cum_t-cum_s)*dtv_s : 0
        {
            int s = tid & 63, tq = tid >> 6;
            float cs = cum_l[s], dv = dtv_l[s];
#pragma unroll
            for (int j = 0; j < 16; j++) {
                int t = tq * 16 + j;
                float g = Gm[s * 68 + t];
                float m = (s <= t) ? g * expf(cum_l[t] - cs) * dv : 0.f;
                BnMt[t * 80 + s] = f2bf(m);
            }
        }
        __syncthreads();
        // Y[t][p] = sum_s M_T[t][s] * X_T[p][s]; wave = t-tile, 4 p-tiles
        {
            f32x4 acc[4] = {};
            const int mrow = wave * 16 + (lane & 15);
            const int kq = (lane >> 4) * 8;
#pragma unroll
            for (int k0 = 0; k0 < 64; k0 += 32) {
                bf16x8 afr = *(const bf16x8*)&BnMt[mrow * 80 + k0 + kq];
#pragma unroll
                for (int ni = 0; ni < 4; ni++) {
                    bf16x8 bfr = *(const bf16x8*)&CnXt[(ni * 16 + (lane & 15)) * 80 + k0 + kq];
                    acc[ni] = __builtin_amdgcn_mfma_f32_16x16x32_bf16(afr, bfr, acc[ni], 0, 0, 0);
                }
            }
            float* ybuf = d ? y_bw : y_fw;
            int quad = lane >> 4, col0 = lane & 15;
#pragma unroll
            for (int r = 0; r < 4; r++) {
                int tl = wave * 16 + quad * 4 + r;
                int tg = tglob(d, c, tl);
                int tout = d ? (tg - 1) : (tg + 1);
                if (tout >= 0 && tout < SEQLEN) {
                    float* yp = ybuf + (size_t)(b * SEQLEN + tout) * D_INNER + h * 64;
#pragma unroll
                    for (int ni = 0; ni < 4; ni++)
                        yp[ni * 16 + col0] = acc[ni][r];
                }
            }
        }
    }
}

// ---------------- K2: per-chunk state S'[p][n] -> bf16 tiles ----------------
__global__ __launch_bounds__(256) void ssd_state_kernel(const unsigned short* __restrict__ xbc,
                                                        const float* __restrict__ cum_tab,
                                                        const float* __restrict__ dtv_tab,
                                                        unsigned short* __restrict__ sreg16)
{
    const int flat = blockIdx.x;
    const int c = flat & 31, h = (flat >> 5) & 15, b = (flat >> 9) & 3, d = flat >> 11;
    const int tid = threadIdx.x;
    const int ty = tid >> 4, tx = tid & 15;

    __shared__ float Bm[64][64];
    __shared__ float Xw[64][64];
    __shared__ float cum_l[64], dtv_l[64];

    if (tid < 64) {
        cum_l[tid] = cum_tab[(size_t)flat * 64 + tid];
        dtv_l[tid] = dtv_tab[(size_t)flat * 64 + tid];
    }
    __syncthreads();
    float clast = cum_l[63];
    for (int idx = tid; idx < 1024; idx += 256) {
        int s = idx >> 4, q = idx & 15;
        int tg = tglob(d, c, s);
        const unsigned short* row = xbc + (size_t)(b * SEQLEN + tg) * CONV_DIM;
        ushort4 ub = *(const ushort4*)(row + 1024 + q * 4);
        ushort4 ux = *(const ushort4*)(row + h * 64 + q * 4);
        float w = expf(clast - cum_l[s]) * dtv_l[s];
        Bm[s][q*4+0] = bf2f(ub.x); Bm[s][q*4+1] = bf2f(ub.y);
        Bm[s][q*4+2] = bf2f(ub.z); Bm[s][q*4+3] = bf2f(ub.w);
        Xw[s][q*4+0] = bf2f(ux.x)*w; Xw[s][q*4+1] = bf2f(ux.y)*w;
        Xw[s][q*4+2] = bf2f(ux.z)*w; Xw[s][q*4+3] = bf2f(ux.w)*w;
    }
    __syncthreads();
    // S'[p][n] = sum_s Xw[s][p] * Bm[s][n]
    float acc[4][4] = {};
    for (int s = 0; s < 64; s++) {
        float4 xv = *(const float4*)&Xw[s][ty * 4];
        float4 bv = *(const float4*)&Bm[s][tx * 4];
        float xx[4] = {xv.x, xv.y, xv.z, xv.w};
        float bb[4] = {bv.x, bv.y, bv.z, bv.w};
#pragma unroll
        for (int i = 0; i < 4; i++)
#pragma unroll
            for (int j = 0; j < 4; j++) acc[i][j] = fmaf(xx[i], bb[j], acc[i][j]);
    }
    unsigned short* st = sreg16 + (size_t)flat * 4096;
#pragma unroll
    for (int i = 0; i < 4; i++) {
        ushort4 o;
        o.x = f2bf(acc[i][0]); o.y = f2bf(acc[i][1]);
        o.z = f2bf(acc[i][2]); o.w = f2bf(acc[i][3]);
        *(ushort4*)&st[(size_t)(ty * 4 + i) * 64 + tx * 4] = o;
    }
}

// ---------------- K3: serial chunk scan, bf16 tiles, fp32 carry, prefetch ----------------
__global__ __launch_bounds__(256) void ssd_chunkscan_kernel(const float* __restrict__ cum_tab,
                                                            unsigned short* __restrict__ sreg16)
{
    const int ps = blockIdx.x & 3;
    const int g  = blockIdx.x >> 2;          // (d,b,h)
    const int tid = threadIdx.x;
    const int base = g * 32;
    const size_t off = (size_t)ps * 1024 + tid * 4;
    float h0 = 0.f, h1 = 0.f, h2 = 0.f, h3 = 0.f;
    ushort4 s = *(ushort4*)(sreg16 + (size_t)base * 4096 + off);
    for (int c = 0; c < 32; c++) {
        int flat = base + c;
        ushort4 snext;
        if (c < 31) snext = *(ushort4*)(sreg16 + (size_t)(flat + 1) * 4096 + off);
        float dec = expf(cum_tab[(size_t)flat * 64 + 63]);
        ushort4 o;
        o.x = f2bf(h0); o.y = f2bf(h1); o.z = f2bf(h2); o.w = f2bf(h3);
        *(ushort4*)(sreg16 + (size_t)flat * 4096 + off) = o;
        h0 = h0 * dec + bf2f(s.x);
        h1 = h1 * dec + bf2f(s.y);
        h2 = h2 * dec + bf2f(s.z);
        h3 = h3 * dec + bf2f(s.w);
        s = snext;
    }
}

// ---------------- K4: inter-chunk, MFMA, natural layouts (no transposes) ----------------
__global__ __launch_bounds__(256) void ssd_inter_mfma(const unsigned short* __restrict__ xbc,
                                                      const float* __restrict__ cum_tab,
                                                      const unsigned short* __restrict__ sreg16,
                                                      float* __restrict__ y_fw,
                                                      float* __restrict__ y_bw)
{
    const int flat = blockIdx.x;
    const int c = flat & 31;
    if (c == 0) return;
    const int h = (flat >> 5) & 15, b = (flat >> 9) & 3, d = flat >> 11;
    const int tid = threadIdx.x, wave = tid >> 6, lane = tid & 63;

    __shared__ unsigned short Cs[64 * 72];   // C[t][n]
    __shared__ unsigned short Hs[64 * 72];   // h'[p][n]
    __shared__ float cum_l[64];

    if (tid < 64) cum_l[tid] = cum_tab[(size_t)flat * 64 + tid];
    {
        int s = tid >> 2, nq = (tid & 3) * 16;
        int tg = tglob(d, c, s);
        const unsigned short* row = xbc + (size_t)(b * SEQLEN + tg) * CONV_DIM + 1088;
        const unsigned short* st = sreg16 + (size_t)flat * 4096 + s * 64;
#pragma unroll
        for (int k = 0; k < 16; k += 4) {
            *(ushort4*)&Cs[s * 72 + nq + k] = *(const ushort4*)(row + nq + k);
            *(ushort4*)&Hs[s * 72 + nq + k] = *(const ushort4*)(st + nq + k);
        }
    }
    __syncthreads();
    // Y[t][p] = sum_n C[t][n] * h'[p][n]; wave = t-tile, 4 p-tiles
    f32x4 acc[4] = {};
    const int fr = lane & 15, kq = (lane >> 4) * 8;
    const int mrow = wave * 16 + fr;
#pragma unroll
    for (int k0 = 0; k0 < 64; k0 += 32) {
        bf16x8 afr = *(const bf16x8*)&Cs[mrow * 72 + k0 + kq];
#pragma unroll
        for (int ni = 0; ni < 4; ni++) {
            bf16x8 bfr = *(const bf16x8*)&Hs[(ni * 16 + fr) * 72 + k0 + kq];
            acc[ni] = __builtin_amdgcn_mfma_f32_16x16x32_bf16(afr, bfr, acc[ni], 0, 0, 0);
        }
    }
    float* ybuf = d ? y_bw : y_fw;
    int quad = lane >> 4, col0 = lane & 15;
#pragma unroll
    for (int r = 0; r < 4; r++) {
        int tl = wave * 16 + quad * 4 + r;
        float a = expf(cum_l[tl]);
        int tg = tglob(d, c, tl);
        int tout = d ? (tg - 1) : (tg + 1);
        if (tout >= 0 && tout < SEQLEN) {
            float* yp = ybuf + (size_t)(b * SEQLEN + tout) * D_INNER + h * 64;
#pragma unroll
            for (int ni = 0; ni < 4; ni++)
                yp[ni * 16 + col0] += acc[ni][r] * a;
        }
    }
}

// ---------------- combine -> bf16 yg ----------------
__global__ __launch_bounds__(256) void combine_kernel(const unsigned short* __restrict__ zx,
                                                      const unsigned short* __restrict__ xbc,
                                                      const float* __restrict__ y_fw,
                                                      const float* __restrict__ y_bw,
                                                      const float* __restrict__ Dp,
                                                      const float* __restrict__ rms_w,
                                                      unsigned short* __restrict__ yg)
{
    int row = blockIdx.x;
    int i = threadIdx.x * 4;
    float4 yf = *(const float4*)(y_fw + (size_t)row * D_INNER + i);
    float4 yb = *(const float4*)(y_bw + (size_t)row * D_INNER + i);
    ushort4 uxs = *(const ushort4*)(xbc + (size_t)row * CONV_DIM + i);
    ushort4 uz  = *(const ushort4*)(zx + (size_t)row * D_IN_PROJ + i);
    float dp = Dp[i >> 6];
    float g[4];
    g[0] = (yf.x + yb.x + bf2f(uxs.x) * dp) * siluf(bf2f(uz.x));
    g[1] = (yf.y + yb.y + bf2f(uxs.y) * dp) * siluf(bf2f(uz.y));
    g[2] = (yf.z + yb.z + bf2f(uxs.z) * dp) * siluf(bf2f(uz.z));
    g[3] = (yf.w + yb.w + bf2f(uxs.w) * dp) * siluf(bf2f(uz.w));
    float ss = g[0]*g[0] + g[1]*g[1] + g[2]*g[2] + g[3]*g[3];
#pragma unroll
    for (int m = 1; m < 64; m <<= 1) ss += __shfl_xor(ss, m, 64);
    __shared__ float red[4];
    if ((threadIdx.x & 63) == 0) red[threadIdx.x >> 6] = ss;
    __syncthreads();
    ss = red[0] + red[1] + red[2] + red[3];
    float scale = rsqrtf(ss * (1.f / D_INNER) + EPS);
    float4 rw = *(const float4*)(rms_w + i);
    ushort4 o;
    o.x = f2bf(g[0] * scale * rw.x); o.y = f2bf(g[1] * scale * rw.y);
    o.z = f2bf(g[2] * scale * rw.z); o.w = f2bf(g[3] * scale * rw.w);
    *(ushort4*)(yg + (size_t)row * D_INNER + i) = o;
}

// ---------------- launch ----------------
extern "C" void kernel_launch(void* const* d_in, const int* in_sizes, int n_in,
                              void* d_out, int out_size, void* d_ws, size_t ws_size,
                              hipStream_t stream)
{
    const float* x         = (const float*)d_in[0];
    const float* ln1_w     = (const float*)d_in[1];
    const float* ln1_b     = (const float*)d_in[2];
    const float* in_proj_w = (const float*)d_in[3];
    const float* conv_w    = (const float*)d_in[4];
    const float* conv_b    = (const float*)d_in[5];
    const float* dt_bias   = (const float*)d_in[6];
    const float* A_log     = (const float*)d_in[7];
    const float* Dp        = (const float*)d_in[8];
    const float* rms_w     = (const float*)d_in[9];
    const float* out_proj_w= (const float*)d_in[10];
    const float* ln2_w     = (const float*)d_in[11];
    const float* ln2_b     = (const float*)d_in[12];
    const float* fc1_w     = (const float*)d_in[13];
    const float* fc1_b     = (const float*)d_in[14];
    const float* fc2_w     = (const float*)d_in[15];
    const float* fc2_b     = (const float*)d_in[16];
    float* out = (float*)d_out;

    float* ws0 = (float*)d_ws;
    unsigned short* zx_bf  = (unsigned short*)ws0;
    unsigned short* xbc_bf = (unsigned short*)(ws0 + OFF_XBCB);
    unsigned short* xT_bf  = (unsigned short*)(ws0 + OFF_XT);
    float* y_fw = ws0 + OFF_YFW;
    float* y_bw = ws0 + OFF_YBW;
    float* sreg = ws0 + OFF_SREG;
    unsigned short* sreg16 = (unsigned short*)sreg;              // bf16 S-tiles (scan phase)
    unsigned short* hA_bf = (unsigned short*)sreg;               // [0, 2097152) floats
    unsigned short* P     = (unsigned short*)(sreg + 2097152);   // [2097152, 2686976)
    unsigned short* yg_bf = (unsigned short*)(sreg + 2686976);   // [2686976, 6881280)
    float* x_res          = sreg + 6881280;                      // [6881280, 11075584)
    unsigned short* f1_bf = (unsigned short*)ws0;    // overlays zx_bf (dead after combine)
    float* cum_tab = out;                            // d_out scratch, overwritten by fc2
    float* dtv_tab = out + 262144;
    float* dtf     = out + 524288;                   // fp32 dt sidecar 8192x32

    // 1. LN1 -> bf16
    ln_kernel<<<dim3(NTOK / 4), dim3(256), 0, stream>>>(x, ln1_w, ln1_b, hA_bf, NTOK);
    // 2. in_proj -> bf16 zx (+ fp32 dt sidecar)
    wconv_kernel<<<dim3(2304 * 512 / 1024), dim3(256), 0, stream>>>(in_proj_w, P, 2208 * 512, 2304 * 512);
    gemm_bf16<<<dim3(18, 64), dim3(256), 0, stream>>>(hA_bf, P, 512, 2208, nullptr, zx_bf, nullptr, nullptr, 0, dtf);
    // 3. conv (bf16 in/out)
    conv_kernel<<<dim3(NTOK * CONV_DIM / 256), dim3(256), 0, stream>>>(zx_bf, conv_w, conv_b, xbc_bf);
    // 4. transpose xs -> xT
    xpose_kernel<<<dim3(32, 16, 4), dim3(256), 0, stream>>>(xbc_bf, xT_bf);
    // 5. tables + boundary zero
    dt_table_kernel<<<dim3(1024), dim3(256), 0, stream>>>(dtf, dt_bias, A_log, cum_tab, dtv_tab);
    bzero_kernel<<<dim3(8), dim3(256), 0, stream>>>(y_fw, y_bw);
    // 6. SSD
    ssd_intra_mfma<<<dim3(1024), dim3(256), 0, stream>>>(xbc_bf, xT_bf, cum_tab, dtv_tab, y_fw, y_bw);
    ssd_state_kernel<<<dim3(4096), dim3(256), 0, stream>>>(xbc_bf, cum_tab, dtv_tab, sreg16);
    ssd_chunkscan_kernel<<<dim3(512), dim3(256), 0, stream>>>(cum_tab, sreg16);
    ssd_inter_mfma<<<dim3(4096), dim3(256), 0, stream>>>(xbc_bf, cum_tab, sreg16, y_fw, y_bw);
    // 7. combine -> bf16 yg
    combine_kernel<<<dim3(NTOK), dim3(256), 0, stream>>>(zx_bf, xbc_bf, y_fw, y_bw, Dp, rms_w, yg_bf);
    // 8. out_proj + residual(x)
    wconv_kernel<<<dim3(512 * 1024 / 1024), dim3(256), 0, stream>>>(out_proj_w, P, 512 * 1024, 512 * 1024);
    gemm_bf16<<<dim3(4, 64), dim3(256), 0, stream>>>(yg_bf, P, 1024, 512, x_res, nullptr, nullptr, x, 0, nullptr);
    // 9. LN2 -> bf16
    ln_kernel<<<dim3(NTOK / 4), dim3(256), 0, stream>>>(x_res, ln2_w, ln2_b, hA_bf, NTOK);
    // 10. fc1 + bias + GELU -> bf16
    wconv_kernel<<<dim3(2048 * 512 / 1024), dim3(256), 0, stream>>>(fc1_w, P, 2048 * 512, 2048 * 512);
    gemm_bf16<<<dim3(16, 64), dim3(256), 0, stream>>>(hA_bf, P, 512, 2048, nullptr, f1_bf, fc1_b, nullptr, 1, nullptr);
    // 11. fc2 + bias + residual
    wconv_kernel<<<dim3(512 * 2048 / 1024), dim3(256), 0, stream>>>(fc2_w, P, 512 * 2048, 512 * 2048);
    gemm_bf16<<<dim3(4, 64), dim3(256), 0, stream>>>(f1_bf, P, 2048, 512, out, nullptr, fc2_b, x_res, 0, nullptr);
}